// Round 4
// baseline (363.052 us; speedup 1.0000x reference)
//
#include <hip/hip_runtime.h>
#include <hip/hip_bf16.h>
#include <cstdint>
#include <cstddef>

#define B_N 4096
typedef short short8 __attribute__((ext_vector_type(8)));
typedef float f32x4 __attribute__((ext_vector_type(4)));

// ws layout (float units)
static constexpr size_t H2B_OFF    = 0;                                  // 4096*4096 ushort
static constexpr size_t POOLED_OFF = 8388608;                            // B*16 f
static constexpr size_t EIDX_OFF   = POOLED_OFF + (size_t)B_N * 16;      // B int
static constexpr size_t EW_OFF     = EIDX_OFF + B_N;                     // B f
static constexpr size_t ORDER_OFF  = EW_OFF + B_N;                       // 4*B int
static constexpr size_t CNT_OFF    = ORDER_OFF + (size_t)4 * B_N;        // 4 int
static constexpr size_t PSUM_OFF   = CNT_OFF + 4;                        // 4 f
static constexpr size_t W2R_OFF    = PSUM_OFF + 4;                       // 73728 ushort = 36864 f
static constexpr size_t W1R_OFF    = W2R_OFF + 36864;                    // 2097152 ushort = 1048576 f
static constexpr size_t W1C_OFF    = W1R_OFF + 1048576;                  // 4096 ushort = 2048 f

__device__ __forceinline__ unsigned int f2bf(float f) {
  unsigned int u = __float_as_uint(f);
  return (u + 0x7fffu + ((u >> 16) & 1u)) >> 16;   // RNE bf16
}
__device__ __forceinline__ unsigned int pkbf(float lo, float hi) {
  float2 f; f.x = lo; f.y = hi;
  __hip_bfloat162 b = __float22bfloat162_rn(f);     // v_cvt_pk_bf16_f32
  union { __hip_bfloat162 b; unsigned u; } c; c.b = b; return c.u;
}

// ---------------- K1: router conv (fp32, SGPR weights) MERGED with weight repacks ----------------
__global__ __launch_bounds__(256) void k_front(const float* __restrict__ x,
    const float* __restrict__ gw, const float* __restrict__ gb, float* __restrict__ pooled,
    const float* __restrict__ wfc1, unsigned short* __restrict__ w1r,
    const float* __restrict__ wc2, unsigned short* __restrict__ w2r,
    const float* __restrict__ wc1, unsigned short* __restrict__ w1c,
    int* __restrict__ counts) {
  __shared__ __align__(16) float xpad[3 * 34 * 34];   // 13872 B (rc path only)
  __shared__ float red[16 * 33];
  const int bid = blockIdx.x, t = threadIdx.x;
  if (bid >= 4096) {            // ---- repack paths ----
    const int rb = bid - 4096;
    if (rb < 2048) {
      const int i = rb * 256 + t;                    // float4 index
      const float4 v = ((const float4*)wfc1)[i];
      ushort4 u;
      u.x = (unsigned short)f2bf(v.x); u.y = (unsigned short)f2bf(v.y);
      u.z = (unsigned short)f2bf(v.z); u.w = (unsigned short)f2bf(v.w);
      *(ushort4*)(w1r + 4 * (size_t)i) = u;
    } else if (rb < 2336) {
      if (rb == 2048 && t < 8) counts[t] = 0;        // counts[4] + psum[4]
      const int i = (rb - 2048) * 256 + t;
      if (i < 4 * 9 * 64 * 32) {
        const int ic = i & 31, j = i >> 5;
        const int oc = j & 63, j2 = j >> 6;
        const int s = j2 % 9, e = j2 / 9;
        w2r[i] = (unsigned short)f2bf(wc2[(((size_t)e * 64 + oc) * 32 + ic) * 9 + s]);
      }
    } else {
      const int i = (rb - 2336) * 256 + t;           // [0, 4096)
      if (i < 4096) {
        const int j = i & 7, n16 = (i >> 3) & 15, q = (i >> 7) & 3, nt = (i >> 9) & 1, e = i >> 10;
        const int k = q * 8 + j;
        float v = 0.f;
        if (k < 27) {
          const int ky = k / 9, c = k % 9, kx = c / 3, ic = c % 3;
          v = wc1[((e * 32 + nt * 16 + n16) * 3 + ic) * 9 + ky * 3 + kx];
        }
        w1c[i] = (unsigned short)f2bf(v);
      }
    }
    return;
  }
  // ---- router conv path ----
  const int b = bid;
  for (int i = t; i < 867; i += 256) ((uint4*)xpad)[i] = make_uint4(0, 0, 0, 0);
  __syncthreads();
  const float4* x4 = (const float4*)(x + (size_t)b * 3072);
  for (int i = t; i < 768; i += 256) {
    float4 v = x4[i];
    int flat = i * 4, ic = flat >> 10, rem = flat & 1023, row = rem >> 5, col = rem & 31;
    float* d = &xpad[ic * 1156 + (row + 1) * 34 + (col + 1)];
    d[0] = v.x; d[1] = v.y; d[2] = v.z; d[3] = v.w;
  }
  __syncthreads();
  const int ty = t >> 4, tx = t & 15;
  float win[3][4][4];
#pragma unroll
  for (int ic = 0; ic < 3; ++ic)
#pragma unroll
  for (int rr = 0; rr < 4; ++rr) {
    const float2* p = (const float2*)&xpad[ic * 1156 + (2 * ty + rr) * 34 + 2 * tx];
    float2 a = p[0], c = p[1];
    win[ic][rr][0] = a.x; win[ic][rr][1] = a.y; win[ic][rr][2] = c.x; win[ic][rr][3] = c.y;
  }
  float sums[16];
#pragma unroll
  for (int oc = 0; oc < 16; ++oc) {
    const float bias = gb[oc];
    float a00 = bias, a01 = bias, a10 = bias, a11 = bias;
#pragma unroll
    for (int ic = 0; ic < 3; ++ic)
#pragma unroll
    for (int ky = 0; ky < 3; ++ky)
#pragma unroll
    for (int kx = 0; kx < 3; ++kx) {
      const float wv = gw[oc * 27 + ic * 9 + ky * 3 + kx];   // block-uniform -> SGPR
      a00 += wv * win[ic][ky][kx];     a01 += wv * win[ic][ky][kx + 1];
      a10 += wv * win[ic][ky + 1][kx]; a11 += wv * win[ic][ky + 1][kx + 1];
    }
    sums[oc] = fmaxf(a00, 0.f) + fmaxf(a01, 0.f) + fmaxf(a10, 0.f) + fmaxf(a11, 0.f);
  }
  const int lane = t & 63, wid = t >> 6;
#pragma unroll
  for (int oc = 0; oc < 16; ++oc) {
    float s = sums[oc];
    s += __shfl_xor(s, 1);
    s += __shfl_xor(s, 2);
    s += __shfl_xor(s, 4);
    sums[oc] = s;
  }
  if ((lane & 7) == 0) {
    const int slot = wid * 8 + (lane >> 3);
#pragma unroll
    for (int oc = 0; oc < 16; ++oc) red[oc * 33 + slot] = sums[oc];
  }
  __syncthreads();
  if (t < 16) {
    float s = 0.f;
#pragma unroll
    for (int i = 0; i < 32; ++i) s += red[t * 33 + i];
    pooled[(size_t)b * 16 + t] = s * (1.f / 1024.f);
  }
}

// ---------------- K2: router FC + softmax + top-1 + bucketing + prob sums ----------------
__global__ __launch_bounds__(256) void k_router_fc(const float* __restrict__ pooled,
    const float* __restrict__ gwfc, const float* __restrict__ gbfc,
    float* __restrict__ probs_out, int* __restrict__ eidx, float* __restrict__ ew,
    int* __restrict__ counts, int* __restrict__ order, float* __restrict__ psum) {
  __shared__ float ps[4];
  const int t = threadIdx.x;
  const int b = blockIdx.x * 256 + t;
  if (t < 4) ps[t] = 0.f;
  __syncthreads();
  const float* pl = pooled + (size_t)b * 16;
  float l[4];
#pragma unroll
  for (int j = 0; j < 4; ++j) {
    float s = gbfc[j];
#pragma unroll
    for (int i = 0; i < 16; ++i) s += pl[i] * gwfc[j * 16 + i];
    l[j] = s;
  }
  const float mx = fmaxf(fmaxf(l[0], l[1]), fmaxf(l[2], l[3]));
  float ex[4], ssum = 0.f;
#pragma unroll
  for (int j = 0; j < 4; ++j) { ex[j] = expf(l[j] - mx); ssum += ex[j]; }
  const float inv = 1.f / ssum;
  float p[4];
#pragma unroll
  for (int j = 0; j < 4; ++j) p[j] = ex[j] * inv;
  *(float4*)(probs_out + (size_t)b * 4) = make_float4(p[0], p[1], p[2], p[3]);
  int em = 0; float pm = p[0];
#pragma unroll
  for (int j = 1; j < 4; ++j) if (p[j] > pm) { pm = p[j]; em = j; }
  eidx[b] = em; ew[b] = pm;
  const int slot = atomicAdd(&counts[em], 1);
  order[em * B_N + slot] = b;
#pragma unroll
  for (int j = 0; j < 4; ++j) atomicAdd(&ps[j], p[j]);
  __syncthreads();
  if (t < 4) atomicAdd(&psum[t], ps[t]);
}

// ---------------- K3: conv1 MFMA (paired-bf16 im2col gather) -> reg-staged h1 -> LDS-union -> conv2 MFMA ----------------
// LDS union: phase 1 = xp0/xp1 (bf16 image, dual parity copies, row stride 103 u16);
//            phase 2 = h1s [18*18 px][36 u16]; phase 3 = h2s floats. 23360 B total.
// Odd row stride (103) makes u16-index parity == tap parity, so every MFMA k-pair
// (p,p+1), p even, is one aligned ds_read_b32 (parity copy selected per lane by n16&1).
// Register history: (256,3) w/ acc[4][4]: 148 live regs, no spill, 3 blk/CU, 76.5 us
// latency-bound (R3: all utils 25-30%). This version splits conv2 into 2 passes of
// 2 n-tiles (acc[4][2]=32 AGPR, pass-1 results staged in 8 scalar floats) to fit the
// (256,4) cap of 128 -> 4 blk/CU. Spill tripwire: WRITE_SIZE must stay ~33 MB.
__global__ __launch_bounds__(256, 4) void k_experts_conv(const float* __restrict__ x,
    const unsigned short* __restrict__ w1c, const float* __restrict__ b1g,
    const unsigned short* __restrict__ w2r, const float* __restrict__ b2g,
    const int* __restrict__ eidx, unsigned short* __restrict__ h2b) {
  __shared__ __align__(16) unsigned char smem[23360];
  unsigned short* const h1s = (unsigned short*)smem;            // [18*18][36] u16
  unsigned short* const xp0 = (unsigned short*)smem;            // val[i], i in [0,3520)
  unsigned short* const xp1 = (unsigned short*)(smem + 7040);   // xp1[j] = val[j+1]
  const int b = blockIdx.x, t = threadIdx.x;
  const int e = __builtin_amdgcn_readfirstlane(eidx[b]);
  {
    uint4 z4 = make_uint4(0, 0, 0, 0);
    uint4* z = (uint4*)smem;
    for (int i = t; i < 880; i += 256) z[i] = z4;   // zero both image copies (14080 B)
  }
  __syncthreads();
  // stage x -> bf16 dual-parity copies (row stride 103 u16, +1 halo ring of zeros)
  const float4* x4 = (const float4*)(x + (size_t)b * 3072);
  for (int i = t; i < 768; i += 256) {
    float4 v = x4[i];
    int flat = i * 4, ic = flat >> 10, rem = flat & 1023, row = rem >> 5, col = rem & 31;
    const int idx = (row + 1) * 103 + (col + 1) * 3 + ic;
    const unsigned short h0 = (unsigned short)pkbf(v.x, 0.f);
    const unsigned short h1v = (unsigned short)pkbf(v.y, 0.f);
    const unsigned short h2 = (unsigned short)pkbf(v.z, 0.f);
    const unsigned short h3 = (unsigned short)pkbf(v.w, 0.f);
    xp0[idx] = h0; xp0[idx + 3] = h1v; xp0[idx + 6] = h2; xp0[idx + 9] = h3;
    xp1[idx - 1] = h0; xp1[idx + 2] = h1v; xp1[idx + 5] = h2; xp1[idx + 8] = h3;
  }
  __syncthreads();
  const int lane = t & 63, wv = t >> 6;
  const int n16 = lane & 15, q = lane >> 4;
  unsigned stag[8][2];   // conv1 outputs staged in regs across the LDS-reuse barrier
  // ---- conv1: MFMA 16x16x32, K=27(+pad), M=pixel col, N=32 oc ----
  {
    const short8 wb0 = *(const short8*)(w1c + (((e * 2 + 0) * 4 + q) * 16 + n16) * 8);
    const short8 wb1 = *(const short8*)(w1c + (((e * 2 + 1) * 4 + q) * 16 + n16) * 8);
    const float bias0 = b1g[e * 32 + n16];
    const float bias1 = b1g[e * 32 + 16 + n16];
    const int pb = n16 & 1;                          // parity of u16 window base
    const char* const c0 = (const char*)xp0;
    const char* const c1m = (const char*)xp1 - 2;    // u32 at odd u16 index i -> c1m + 2i
    const char* const pA = pb ? c1m : c0;            // afA rows: base parity pb
    const char* const pB = pb ? c0 : c1m;            // afB rows (+103 u16): parity flips
    // per-q byte offsets of the four k-pair u32 reads (relative to window base*2)
    const int o0 = (q == 0) ? 0  : (q == 1) ? 208 : (q == 2) ? 220 : 424;
    const int o1 = (q == 0) ? 4  : (q == 1) ? 208 : (q == 2) ? 412 : 428;
    const int o2 = (q == 0) ? 8  : (q == 1) ? 212 : (q == 2) ? 416 : 424;  // q3: dummy
    const int o3 = (q == 0) ? 12 : (q == 1) ? 216 : (q == 2) ? 420 : 428;  // q3: dummy
    const int bbase = 1648 * wv + 6 * n16;
    const char* const A0 = pA + o0 + bbase;
    const char* const A1 = pA + o1 + bbase;
    const char* const A2 = pA + o2 + bbase;
    const char* const A3 = pA + o3 + bbase;
    const char* const B0 = pB + 206 + o0 + bbase;
    const char* const B1 = pB + 206 + o1 + bbase;
    const char* const B2 = pB + 206 + o2 + bbase;
    const char* const B3 = pB + 206 + o3 + bbase;
    const char* const XS = (const char*)xp0 + bbase; // straddle u16 reads (q==1 pair (8,9))
    const bool isq1 = (q == 1), isq3 = (q == 3);
#pragma unroll
    for (int pid = 0; pid < 8; ++pid) {
      const int D = 412 * (pid >> 1) + 96 * (pid & 1);   // compile-time per iteration
      union { unsigned u[4]; short8 s; } fa, fb;
      {
        const unsigned a0 = *(const unsigned*)(A0 + D);
        const unsigned a1 = *(const unsigned*)(A1 + D);
        const unsigned a2 = *(const unsigned*)(A2 + D);
        const unsigned a3 = *(const unsigned*)(A3 + D);
        const unsigned s0 = *(const unsigned short*)(XS + D + 16);   // tap 8
        const unsigned s1 = *(const unsigned short*)(XS + D + 206);  // tap 9 (row+1)
        fa.u[0] = isq1 ? (s0 | (s1 << 16)) : a0;
        fa.u[1] = a1;
        fa.u[2] = isq3 ? 0u : a2;
        fa.u[3] = isq3 ? 0u : a3;
      }
      {
        const unsigned b0 = *(const unsigned*)(B0 + D);
        const unsigned b1 = *(const unsigned*)(B1 + D);
        const unsigned b2 = *(const unsigned*)(B2 + D);
        const unsigned b3 = *(const unsigned*)(B3 + D);
        const unsigned s0 = *(const unsigned short*)(XS + D + 222);
        const unsigned s1 = *(const unsigned short*)(XS + D + 412);
        fb.u[0] = isq1 ? (s0 | (s1 << 16)) : b0;
        fb.u[1] = b1;
        fb.u[2] = isq3 ? 0u : b2;
        fb.u[3] = isq3 ? 0u : b3;
      }
      f32x4 aA0 = {bias0, bias0, bias0, bias0}, aA1 = {bias1, bias1, bias1, bias1};
      f32x4 aB0 = aA0, aB1 = aA1;
      aA0 = __builtin_amdgcn_mfma_f32_16x16x32_bf16(fa.s, wb0, aA0, 0, 0, 0);
      aA1 = __builtin_amdgcn_mfma_f32_16x16x32_bf16(fa.s, wb1, aA1, 0, 0, 0);
      aB0 = __builtin_amdgcn_mfma_f32_16x16x32_bf16(fb.s, wb0, aB0, 0, 0, 0);
      aB1 = __builtin_amdgcn_mfma_f32_16x16x32_bf16(fb.s, wb1, aB1, 0, 0, 0);
      // 2x2 maxpool + relu, pack pairs (p00,p10),(p01,p11) with v_cvt_pk_bf16_f32
      const float p00 = fmaxf(fmaxf(fmaxf(aA0[0], aA0[1]), fmaxf(aB0[0], aB0[1])), 0.f);
      const float p01 = fmaxf(fmaxf(fmaxf(aA0[2], aA0[3]), fmaxf(aB0[2], aB0[3])), 0.f);
      const float p10 = fmaxf(fmaxf(fmaxf(aA1[0], aA1[1]), fmaxf(aB1[0], aB1[1])), 0.f);
      const float p11 = fmaxf(fmaxf(fmaxf(aA1[2], aA1[3]), fmaxf(aB1[2], aB1[3])), 0.f);
      stag[pid][0] = pkbf(p00, p10);
      stag[pid][1] = pkbf(p01, p11);
    }
  }
  __syncthreads();   // image copies dead; LDS becomes h1s
  // halo ring zero + interior h1 writes (disjoint addresses, same phase)
  if (t < 68) {
    int py, px;
    if (t < 18) { py = 0; px = t; }
    else if (t < 36) { py = 17; px = t - 18; }
    else if (t < 52) { py = t - 35; px = 0; }
    else { py = t - 51; px = 17; }
    uint2* d = (uint2*)&h1s[(py * 18 + px) * 36];
    const uint2 z2 = make_uint2(0, 0);
#pragma unroll
    for (int i2 = 0; i2 < 9; ++i2) d[i2] = z2;
  }
  {
    unsigned short* const wp = h1s + 2592 * wv + 72 * q + n16 + 684;
#pragma unroll
    for (int pid = 0; pid < 8; ++pid) {
      const int W = 648 * (pid >> 1) + 288 * (pid & 1);  // compile-time
      const unsigned v0 = stag[pid][0], v1 = stag[pid][1];
      wp[W]      = (unsigned short)v0;          // oc = n16
      wp[W + 16] = (unsigned short)(v0 >> 16);  // oc = 16+n16
      wp[W + 36] = (unsigned short)v1;          // next pixel
      wp[W + 52] = (unsigned short)(v1 >> 16);
    }
  }
  __syncthreads();
  // ---- conv2: 2 passes x 2 n-tiles (acc 32 regs/pass); B streamed from global (L2) ----
  {
    const unsigned short* const wb2 = w2r + (size_t)e * 18432 + n16 * 32 + q * 8;
    float2 pres[2][2][2];                       // [pass][u2][ntl], static idx only
#pragma unroll
    for (int pass = 0; pass < 2; ++pass) {
      const unsigned short* wbase = wb2 + (size_t)(pass * 2) * 512;
      const float bz0 = b2g[e * 64 + (pass * 2) * 16 + n16];
      const float bz1 = b2g[e * 64 + (pass * 2 + 1) * 16 + n16];
      f32x4 acc[4][2];
#pragma unroll
      for (int mt4 = 0; mt4 < 4; ++mt4) {
        acc[mt4][0][0] = bz0; acc[mt4][0][1] = bz0; acc[mt4][0][2] = bz0; acc[mt4][0][3] = bz0;
        acc[mt4][1][0] = bz1; acc[mt4][1][1] = bz1; acc[mt4][1][2] = bz1; acc[mt4][1][3] = bz1;
      }
      short8 Bc[2];
      Bc[0] = *(const short8*)(wbase);
      Bc[1] = *(const short8*)(wbase + 512);
#pragma unroll
      for (int s = 0; s < 9; ++s) {
        const int ky = s / 3, kx = s % 3;
        short8 Bn[2];
        if (s < 8) {
          Bn[0] = *(const short8*)(wbase + (s + 1) * 2048);
          Bn[1] = *(const short8*)(wbase + (s + 1) * 2048 + 512);
        }
#pragma unroll
        for (int mt4 = 0; mt4 < 4; ++mt4) {
          const int mt = wv * 4 + mt4;
          const short8 af = *(const short8*)&h1s[((mt + ky) * 18 + n16 + kx) * 36 + q * 8];
          acc[mt4][0] = __builtin_amdgcn_mfma_f32_16x16x32_bf16(af, Bc[0], acc[mt4][0], 0, 0, 0);
          acc[mt4][1] = __builtin_amdgcn_mfma_f32_16x16x32_bf16(af, Bc[1], acc[mt4][1], 0, 0, 0);
        }
        if (s < 8) { Bc[0] = Bn[0]; Bc[1] = Bn[1]; }
      }
      // 2x2 maxpool + relu into regs (acc freed before next pass)
#pragma unroll
      for (int u2 = 0; u2 < 2; ++u2)
#pragma unroll
        for (int ntl = 0; ntl < 2; ++ntl) {
          const f32x4 a = acc[2 * u2][ntl], c = acc[2 * u2 + 1][ntl];
          pres[pass][u2][ntl].x = fmaxf(fmaxf(fmaxf(a[0], a[1]), fmaxf(c[0], c[1])), 0.f);
          pres[pass][u2][ntl].y = fmaxf(fmaxf(fmaxf(a[2], a[3]), fmaxf(c[2], c[3])), 0.f);
        }
    }
    __syncthreads();                        // all MFMA reads of h1s done (both passes)
    float* h2s = (float*)h1s;               // [oc][68]
#pragma unroll
    for (int pass = 0; pass < 2; ++pass)
#pragma unroll
      for (int u2 = 0; u2 < 2; ++u2) {
        const int py = wv * 2 + u2;
#pragma unroll
        for (int ntl = 0; ntl < 2; ++ntl) {
          const int nt = pass * 2 + ntl;
          *(float2*)&h2s[(nt * 16 + n16) * 68 + py * 8 + 2 * q] = pres[pass][u2][ntl];
        }
      }
  }
  __syncthreads();
  {
    const float* h2s = (const float*)h1s;
    unsigned short* dst = h2b + (size_t)b * 4096;
#pragma unroll
    for (int j = 0; j < 2; ++j) {
      const int f = 8 * (t + 256 * j);          // flat k = oc*64+py*8+px
      const float* src = &h2s[(f >> 6) * 68 + (f & 63)];
      float4 v0 = *(const float4*)src;
      float4 v1 = *(const float4*)(src + 4);
      unsigned int p0 = pkbf(v0.x, v0.y);
      unsigned int p1 = pkbf(v0.z, v0.w);
      unsigned int p2 = pkbf(v1.x, v1.y);
      unsigned int p3 = pkbf(v1.z, v1.w);
      *(uint4*)(dst + f) = make_uint4(p0, p1, p2, p3);
    }
  }
}

// ---------------- K4: bucketed fc1 (M=16, bf16 MFMA, reg-prefetch) + relu + fc2 fp32 + aux ----------------
__global__ __launch_bounds__(256) void k_fc(const unsigned short* __restrict__ h2b,
    const unsigned short* __restrict__ w1r, const float* __restrict__ b1g,
    const float* __restrict__ w2g, const float* __restrict__ b2g,
    const int* __restrict__ counts, const int* __restrict__ order,
    const float* __restrict__ ew, const float* __restrict__ psum,
    float* __restrict__ outp) {
  const int bid = blockIdx.x;
  if (bid == 0 && threadIdx.x == 0) {        // aux loss (before any early-exit)
    float a = 0.f;
#pragma unroll
    for (int j = 0; j < 4; ++j) {
      const float mp = psum[j] * (1.f / 4096.f) - 0.25f;
      a += mp * mp;
    }
    outp[57344] = a * 0.25f;
  }
  const int e = bid >> 8, tile = bid & 255;
  const int n = counts[e];
  const int base = tile * 16;
  if (base >= n) return;
  const int t = threadIdx.x;
  __shared__ int sb[16];
  __shared__ float wgt[16];
  __shared__ __align__(16) unsigned short As[16][280];   // 16 x 256 k, stride 280 (bank-clean)
  __shared__ float f1s[16 * 132];
  if (t < 16) {
    const int idx = base + t;
    const int s = order[e * B_N + ((idx < n) ? idx : base)];
    sb[t] = s; wgt[t] = ew[s];
  }
  __syncthreads();
  const int lane = t & 63, wv = t >> 6;
  const int n16 = lane & 15, q = lane >> 4;
  const int oc0 = wv * 32 + n16;           // n-tile 2*wv
  const int oc1 = wv * 32 + 16 + n16;      // n-tile 2*wv+1
  const unsigned short* wb0 = w1r + ((size_t)(e * 128 + oc0)) * 4096 + q * 8;
  const unsigned short* wb1 = w1r + ((size_t)(e * 128 + oc1)) * 4096 + q * 8;
  f32x4 acc0 = {0.f, 0.f, 0.f, 0.f}, acc1 = {0.f, 0.f, 0.f, 0.f};
  const int ldrow = t >> 4, ldseg = t & 15;
  const unsigned short* asrc = h2b + (size_t)sb[ldrow] * 4096;
  uint4 r0 = *(const uint4*)(asrc + ldseg * 8);            // prefetch kc=0
  uint4 r1 = *(const uint4*)(asrc + (ldseg + 16) * 8);
  for (int kc = 0; kc < 4096; kc += 256) {
    *(uint4*)&As[ldrow][ldseg * 8] = r0;
    *(uint4*)&As[ldrow][(ldseg + 16) * 8] = r1;
    __syncthreads();
    if (kc + 256 < 4096) {                                 // prefetch next chunk (overlaps MFMA)
      r0 = *(const uint4*)(asrc + (kc + 256) + ldseg * 8);
      r1 = *(const uint4*)(asrc + (kc + 256) + (ldseg + 16) * 8);
    }
#pragma unroll
    for (int ks = 0; ks < 8; ++ks) {
      const short8 af = *(const short8*)&As[n16][ks * 32 + q * 8];   // A[m=n16][k]
      const short8 bf0 = *(const short8*)(wb0 + kc + ks * 32);       // B[k][n=oc0]
      const short8 bf1 = *(const short8*)(wb1 + kc + ks * 32);
      acc0 = __builtin_amdgcn_mfma_f32_16x16x32_bf16(af, bf0, acc0, 0, 0, 0);
      acc1 = __builtin_amdgcn_mfma_f32_16x16x32_bf16(af, bf1, acc1, 0, 0, 0);
    }
    __syncthreads();
  }
  // C layout: row m = q*4+r (sample), col = n16 (oc)
  const float* b1 = b1g + e * 128;
  const float bb0 = b1[oc0], bb1 = b1[oc1];
#pragma unroll
  for (int r = 0; r < 4; ++r) {
    const int m = q * 4 + r;
    f1s[m * 132 + oc0] = fmaxf(acc0[r] + bb0, 0.f);
    f1s[m * 132 + oc1] = fmaxf(acc1[r] + bb1, 0.f);
  }
  __syncthreads();
  int m = n - base; if (m > 16) m = 16;
  if (t < 160) {
    const int r = t / 10, o = t - r * 10;
    if (r < m) {
      const float* w2 = w2g + (e * 10 + o) * 128;
      float s = b2g[e * 10 + o];
#pragma unroll 8
      for (int c = 0; c < 128; ++c) s += f1s[r * 132 + c] * w2[c];
      outp[(size_t)sb[r] * 10 + o] = s * wgt[r];
    }
  }
}

extern "C" void kernel_launch(void* const* d_in, const int* in_sizes, int n_in,
                              void* d_out, int out_size, void* d_ws, size_t ws_size,
                              hipStream_t stream) {
  const float* x        = (const float*)d_in[0];
  const float* gw_conv  = (const float*)d_in[1];
  const float* gb_conv  = (const float*)d_in[2];
  const float* gw_fc    = (const float*)d_in[3];
  const float* gb_fc    = (const float*)d_in[4];
  const float* ew_conv1 = (const float*)d_in[5];
  const float* eb_conv1 = (const float*)d_in[6];
  const float* ew_conv2 = (const float*)d_in[7];
  const float* eb_conv2 = (const float*)d_in[8];
  const float* ew_fc1   = (const float*)d_in[9];
  const float* eb_fc1   = (const float*)d_in[10];
  const float* ew_fc2   = (const float*)d_in[11];
  const float* eb_fc2   = (const float*)d_in[12];
  float* out = (float*)d_out;
  float* ws  = (float*)d_ws;

  unsigned short* h2b = (unsigned short*)(ws + H2B_OFF);
  float* pooled = ws + POOLED_OFF;
  int*   eidx   = (int*)(ws + EIDX_OFF);
  float* ew     = ws + EW_OFF;
  int*   order  = (int*)(ws + ORDER_OFF);
  int*   counts = (int*)(ws + CNT_OFF);
  float* psum   = ws + PSUM_OFF;
  unsigned short* w2r = (unsigned short*)(ws + W2R_OFF);
  unsigned short* w1r = (unsigned short*)(ws + W1R_OFF);
  unsigned short* w1c = (unsigned short*)(ws + W1C_OFF);

  k_front<<<6448, 256, 0, stream>>>(x, gw_conv, gb_conv, pooled,
                                    ew_fc1, w1r, ew_conv2, w2r, ew_conv1, w1c, counts);
  k_router_fc<<<16, 256, 0, stream>>>(pooled, gw_fc, gb_fc, out + 40960, eidx, ew,
                                      counts, order, psum);
  k_experts_conv<<<4096, 256, 0, stream>>>(x, w1c, eb_conv1, w2r, eb_conv2,
                                           eidx, h2b);
  k_fc<<<1024, 256, 0, stream>>>(h2b, w1r, eb_fc1, ew_fc2, eb_fc2,
                                 counts, order, ew, psum, out);
}

// Round 5
// 356.924 us; speedup vs baseline: 1.0172x; 1.0172x over previous
//
#include <hip/hip_runtime.h>
#include <hip/hip_bf16.h>
#include <cstdint>
#include <cstddef>

#define B_N 4096
typedef short short8 __attribute__((ext_vector_type(8)));
typedef float f32x4 __attribute__((ext_vector_type(4)));

// ws layout (float units)
static constexpr size_t H2B_OFF    = 0;                                  // 4096*4096 ushort
static constexpr size_t POOLED_OFF = 8388608;                            // B*16 f
static constexpr size_t EIDX_OFF   = POOLED_OFF + (size_t)B_N * 16;      // B int
static constexpr size_t EW_OFF     = EIDX_OFF + B_N;                     // B f
static constexpr size_t ORDER_OFF  = EW_OFF + B_N;                       // 4*B int
static constexpr size_t CNT_OFF    = ORDER_OFF + (size_t)4 * B_N;        // 4 int
static constexpr size_t PSUM_OFF   = CNT_OFF + 4;                        // 4 f
static constexpr size_t W2R_OFF    = PSUM_OFF + 4;                       // 73728 ushort = 36864 f
static constexpr size_t W1R_OFF    = W2R_OFF + 36864;                    // 2097152 ushort = 1048576 f
static constexpr size_t W1C_OFF    = W1R_OFF + 1048576;                  // 4096 ushort = 2048 f

__device__ __forceinline__ unsigned int f2bf(float f) {
  unsigned int u = __float_as_uint(f);
  return (u + 0x7fffu + ((u >> 16) & 1u)) >> 16;   // RNE bf16
}
__device__ __forceinline__ unsigned int pkbf(float lo, float hi) {
  float2 f; f.x = lo; f.y = hi;
  __hip_bfloat162 b = __float22bfloat162_rn(f);     // v_cvt_pk_bf16_f32
  union { __hip_bfloat162 b; unsigned u; } c; c.b = b; return c.u;
}

// ---------------- K1: router conv (fp32, SGPR weights) MERGED with weight repacks ----------------
__global__ __launch_bounds__(256) void k_front(const float* __restrict__ x,
    const float* __restrict__ gw, const float* __restrict__ gb, float* __restrict__ pooled,
    const float* __restrict__ wfc1, unsigned short* __restrict__ w1r,
    const float* __restrict__ wc2, unsigned short* __restrict__ w2r,
    const float* __restrict__ wc1, unsigned short* __restrict__ w1c,
    int* __restrict__ counts) {
  __shared__ __align__(16) float xpad[3 * 34 * 34];   // 13872 B (rc path only)
  __shared__ float red[16 * 33];
  const int bid = blockIdx.x, t = threadIdx.x;
  if (bid >= 4096) {            // ---- repack paths ----
    const int rb = bid - 4096;
    if (rb < 2048) {
      const int i = rb * 256 + t;                    // float4 index
      const float4 v = ((const float4*)wfc1)[i];
      ushort4 u;
      u.x = (unsigned short)f2bf(v.x); u.y = (unsigned short)f2bf(v.y);
      u.z = (unsigned short)f2bf(v.z); u.w = (unsigned short)f2bf(v.w);
      *(ushort4*)(w1r + 4 * (size_t)i) = u;
    } else if (rb < 2336) {
      if (rb == 2048 && t < 8) counts[t] = 0;        // counts[4] + psum[4]
      const int i = (rb - 2048) * 256 + t;
      if (i < 4 * 9 * 64 * 32) {
        const int ic = i & 31, j = i >> 5;
        const int oc = j & 63, j2 = j >> 6;
        const int s = j2 % 9, e = j2 / 9;
        w2r[i] = (unsigned short)f2bf(wc2[(((size_t)e * 64 + oc) * 32 + ic) * 9 + s]);
      }
    } else {
      const int i = (rb - 2336) * 256 + t;           // [0, 4096)
      if (i < 4096) {
        const int j = i & 7, n16 = (i >> 3) & 15, q = (i >> 7) & 3, nt = (i >> 9) & 1, e = i >> 10;
        const int k = q * 8 + j;
        float v = 0.f;
        if (k < 27) {
          const int ky = k / 9, c = k % 9, kx = c / 3, ic = c % 3;
          v = wc1[((e * 32 + nt * 16 + n16) * 3 + ic) * 9 + ky * 3 + kx];
        }
        w1c[i] = (unsigned short)f2bf(v);
      }
    }
    return;
  }
  // ---- router conv path ----
  const int b = bid;
  for (int i = t; i < 867; i += 256) ((uint4*)xpad)[i] = make_uint4(0, 0, 0, 0);
  __syncthreads();
  const float4* x4 = (const float4*)(x + (size_t)b * 3072);
  for (int i = t; i < 768; i += 256) {
    float4 v = x4[i];
    int flat = i * 4, ic = flat >> 10, rem = flat & 1023, row = rem >> 5, col = rem & 31;
    float* d = &xpad[ic * 1156 + (row + 1) * 34 + (col + 1)];
    d[0] = v.x; d[1] = v.y; d[2] = v.z; d[3] = v.w;
  }
  __syncthreads();
  const int ty = t >> 4, tx = t & 15;
  float win[3][4][4];
#pragma unroll
  for (int ic = 0; ic < 3; ++ic)
#pragma unroll
  for (int rr = 0; rr < 4; ++rr) {
    const float2* p = (const float2*)&xpad[ic * 1156 + (2 * ty + rr) * 34 + 2 * tx];
    float2 a = p[0], c = p[1];
    win[ic][rr][0] = a.x; win[ic][rr][1] = a.y; win[ic][rr][2] = c.x; win[ic][rr][3] = c.y;
  }
  float sums[16];
#pragma unroll
  for (int oc = 0; oc < 16; ++oc) {
    const float bias = gb[oc];
    float a00 = bias, a01 = bias, a10 = bias, a11 = bias;
#pragma unroll
    for (int ic = 0; ic < 3; ++ic)
#pragma unroll
    for (int ky = 0; ky < 3; ++ky)
#pragma unroll
    for (int kx = 0; kx < 3; ++kx) {
      const float wv = gw[oc * 27 + ic * 9 + ky * 3 + kx];   // block-uniform -> SGPR
      a00 += wv * win[ic][ky][kx];     a01 += wv * win[ic][ky][kx + 1];
      a10 += wv * win[ic][ky + 1][kx]; a11 += wv * win[ic][ky + 1][kx + 1];
    }
    sums[oc] = fmaxf(a00, 0.f) + fmaxf(a01, 0.f) + fmaxf(a10, 0.f) + fmaxf(a11, 0.f);
  }
  const int lane = t & 63, wid = t >> 6;
#pragma unroll
  for (int oc = 0; oc < 16; ++oc) {
    float s = sums[oc];
    s += __shfl_xor(s, 1);
    s += __shfl_xor(s, 2);
    s += __shfl_xor(s, 4);
    sums[oc] = s;
  }
  if ((lane & 7) == 0) {
    const int slot = wid * 8 + (lane >> 3);
#pragma unroll
    for (int oc = 0; oc < 16; ++oc) red[oc * 33 + slot] = sums[oc];
  }
  __syncthreads();
  if (t < 16) {
    float s = 0.f;
#pragma unroll
    for (int i = 0; i < 32; ++i) s += red[t * 33 + i];
    pooled[(size_t)b * 16 + t] = s * (1.f / 1024.f);
  }
}

// ---------------- K2: router FC + softmax + top-1 + bucketing + prob sums ----------------
__global__ __launch_bounds__(256) void k_router_fc(const float* __restrict__ pooled,
    const float* __restrict__ gwfc, const float* __restrict__ gbfc,
    float* __restrict__ probs_out, int* __restrict__ eidx, float* __restrict__ ew,
    int* __restrict__ counts, int* __restrict__ order, float* __restrict__ psum) {
  __shared__ float ps[4];
  const int t = threadIdx.x;
  const int b = blockIdx.x * 256 + t;
  if (t < 4) ps[t] = 0.f;
  __syncthreads();
  const float* pl = pooled + (size_t)b * 16;
  float l[4];
#pragma unroll
  for (int j = 0; j < 4; ++j) {
    float s = gbfc[j];
#pragma unroll
    for (int i = 0; i < 16; ++i) s += pl[i] * gwfc[j * 16 + i];
    l[j] = s;
  }
  const float mx = fmaxf(fmaxf(l[0], l[1]), fmaxf(l[2], l[3]));
  float ex[4], ssum = 0.f;
#pragma unroll
  for (int j = 0; j < 4; ++j) { ex[j] = expf(l[j] - mx); ssum += ex[j]; }
  const float inv = 1.f / ssum;
  float p[4];
#pragma unroll
  for (int j = 0; j < 4; ++j) p[j] = ex[j] * inv;
  *(float4*)(probs_out + (size_t)b * 4) = make_float4(p[0], p[1], p[2], p[3]);
  int em = 0; float pm = p[0];
#pragma unroll
  for (int j = 1; j < 4; ++j) if (p[j] > pm) { pm = p[j]; em = j; }
  eidx[b] = em; ew[b] = pm;
  const int slot = atomicAdd(&counts[em], 1);
  order[em * B_N + slot] = b;
#pragma unroll
  for (int j = 0; j < 4; ++j) atomicAdd(&ps[j], p[j]);
  __syncthreads();
  if (t < 4) atomicAdd(&psum[t], ps[t]);
}

// ---- conv1 A-fragment gather from ic-interleaved fp32 image (packed bf16 cvt) ----
__device__ __forceinline__ short8 gather_a(const float* __restrict__ base,
                                           const int* goff, bool isq1, bool isq3) {
  const float a0 = base[goff[0]];
  float       a1 = base[goff[0] + 1];
  const float b0 = base[goff[1]], b1 = base[goff[1] + 1];
  const float c0 = base[goff[2]], c1 = base[goff[2] + 1];
  const float d0 = base[goff[3]], d1 = base[goff[3] + 1];
  a1 = isq1 ? base[102] : a1;          // patch: p=9 (row 1, c 0) for q==1 lanes
  union { unsigned u[4]; short8 s; } r;
  r.u[0] = pkbf(a0, a1);
  r.u[1] = pkbf(b0, isq3 ? 0.f : b1);  // p>=27 zero padding (q==3)
  r.u[2] = isq3 ? 0u : pkbf(c0, c1);
  r.u[3] = isq3 ? 0u : pkbf(d0, d1);
  return r.s;
}

// ---------------- K3: conv1 MFMA (im2col) -> h1 bf16 LDS (36-stride, bank-clean) -> conv2 MFMA -> h2 bf16 ----------------
// REVERTED to the verified 69-us baseline (R0). Four restructure attempts (LDS-union
// + bf16 dual-parity gather; launch_bounds 4/5 waves; conv2 2-pass split) all regressed:
// the register floor is ~148 total (incl 64 AGPR acc) -> any cap <= 128 spills to
// scratch (R1: 1.35 GB, R2: 124 MB, R4: 390 MB), and at equal occupancy the gather's
// VALU savings were off the critical path (R3: 76.5 us vs 69 us, VALUBusy 51->30).
__global__ __launch_bounds__(256, 3) void k_experts_conv(const float* __restrict__ x,
    const unsigned short* __restrict__ w1c, const float* __restrict__ b1g,
    const unsigned short* __restrict__ w2r, const float* __restrict__ b2g,
    const int* __restrict__ eidx, unsigned short* __restrict__ h2b) {
  __shared__ __align__(16) float xpi[3572];                  // [34 rows][34 cols][3 ic] +pad, 14288 B
  __shared__ __align__(16) unsigned short h1s[18 * 18 * 36]; // 23328 B, pixel stride 36 u16 (bank pad)
  const int b = blockIdx.x, t = threadIdx.x;
  const int e = __builtin_amdgcn_readfirstlane(eidx[b]);
  {
    uint4 z4 = make_uint4(0, 0, 0, 0);
    uint4* z1 = (uint4*)h1s;
    for (int i = t; i < 1458; i += 256) z1[i] = z4;
    uint4* z2 = (uint4*)xpi;
    for (int i = t; i < 893; i += 256) z2[i] = z4;
  }
  __syncthreads();
  const float4* x4 = (const float4*)(x + (size_t)b * 3072);
  for (int i = t; i < 768; i += 256) {
    float4 v = x4[i];
    int flat = i * 4, ic = flat >> 10, rem = flat & 1023, row = rem >> 5, col = rem & 31;
    float* d = &xpi[(row + 1) * 102 + (col + 1) * 3 + ic];
    d[0] = v.x; d[3] = v.y; d[6] = v.z; d[9] = v.w;
  }
  __syncthreads();
  const int lane = t & 63, wv = t >> 6;
  const int n16 = lane & 15, q = lane >> 4;
  // ---- conv1: MFMA 16x16x32, K=27(+pad), M=pixel col, N=32 oc ----
  {
    const bool isq1 = (q == 1), isq3 = (q == 3);
    const short8 wb0 = *(const short8*)(w1c + (((e * 2 + 0) * 4 + q) * 16 + n16) * 8);
    const short8 wb1 = *(const short8*)(w1c + (((e * 2 + 1) * 4 + q) * 16 + n16) * 8);
    const float bias0 = b1g[e * 32 + n16];
    const float bias1 = b1g[e * 32 + 16 + n16];
    int goff[4];
#pragma unroll
    for (int t4 = 0; t4 < 4; ++t4) {
      const int p0 = q * 8 + 2 * t4;
      const int r = (p0 * 939) >> 13;        // p0/9 for p0<32
      goff[t4] = r * 102 + (p0 - 9 * r);
    }
    for (int pid = 0; pid < 8; ++pid) {
      const int pairid = wv * 8 + pid;
      const int yp = pairid >> 1, xh = pairid & 1;
      const float* baseA = &xpi[(2 * yp) * 102 + (xh * 16 + n16) * 3];
      const short8 afA = gather_a(baseA, goff, isq1, isq3);
      const short8 afB = gather_a(baseA + 102, goff, isq1, isq3);
      f32x4 aA0 = {bias0, bias0, bias0, bias0}, aA1 = {bias1, bias1, bias1, bias1};
      f32x4 aB0 = aA0, aB1 = aA1;
      aA0 = __builtin_amdgcn_mfma_f32_16x16x32_bf16(afA, wb0, aA0, 0, 0, 0);
      aA1 = __builtin_amdgcn_mfma_f32_16x16x32_bf16(afA, wb1, aA1, 0, 0, 0);
      aB0 = __builtin_amdgcn_mfma_f32_16x16x32_bf16(afB, wb0, aB0, 0, 0, 0);
      aB1 = __builtin_amdgcn_mfma_f32_16x16x32_bf16(afB, wb1, aB1, 0, 0, 0);
      // 2x2 maxpool + relu -> h1s[pix][ic] bf16 (pixel stride 36)
      const int px = xh * 8 + 2 * q;
      unsigned short* hw = &h1s[((yp + 1) * 18 + (px + 1)) * 36];
      const float p00 = fmaxf(fmaxf(fmaxf(aA0[0], aA0[1]), fmaxf(aB0[0], aB0[1])), 0.f);
      const float p01 = fmaxf(fmaxf(fmaxf(aA0[2], aA0[3]), fmaxf(aB0[2], aB0[3])), 0.f);
      const float p10 = fmaxf(fmaxf(fmaxf(aA1[0], aA1[1]), fmaxf(aB1[0], aB1[1])), 0.f);
      const float p11 = fmaxf(fmaxf(fmaxf(aA1[2], aA1[3]), fmaxf(aB1[2], aB1[3])), 0.f);
      hw[n16]           = (unsigned short)f2bf(p00);
      hw[16 + n16]      = (unsigned short)f2bf(p10);
      hw[36 + n16]      = (unsigned short)f2bf(p01);
      hw[36 + 16 + n16] = (unsigned short)f2bf(p11);
    }
  }
  __syncthreads();
  // ---- conv2: wave = 4 rows x all 64 oc; B streamed from global (L2) with prefetch ----
  {
    const unsigned short* wbase = w2r + (size_t)e * 18432 + n16 * 32 + q * 8;
    float bz[4];
#pragma unroll
    for (int nt = 0; nt < 4; ++nt) bz[nt] = b2g[e * 64 + nt * 16 + n16];
    f32x4 acc[4][4];
#pragma unroll
    for (int mt4 = 0; mt4 < 4; ++mt4)
#pragma unroll
      for (int nt = 0; nt < 4; ++nt) {
        acc[mt4][nt][0] = bz[nt]; acc[mt4][nt][1] = bz[nt];
        acc[mt4][nt][2] = bz[nt]; acc[mt4][nt][3] = bz[nt];
      }
    short8 Bc[4];
#pragma unroll
    for (int nt = 0; nt < 4; ++nt) Bc[nt] = *(const short8*)(wbase + nt * 512);
#pragma unroll
    for (int s = 0; s < 9; ++s) {
      const int ky = s / 3, kx = s % 3;
      short8 Bn[4];
      if (s < 8) {
#pragma unroll
        for (int nt = 0; nt < 4; ++nt)
          Bn[nt] = *(const short8*)(wbase + (s + 1) * 2048 + nt * 512);
      }
#pragma unroll
      for (int mt4 = 0; mt4 < 4; ++mt4) {
        const int mt = wv * 4 + mt4;
        const short8 af = *(const short8*)&h1s[((mt + ky) * 18 + n16 + kx) * 36 + q * 8];
#pragma unroll
        for (int nt = 0; nt < 4; ++nt)
          acc[mt4][nt] = __builtin_amdgcn_mfma_f32_16x16x32_bf16(af, Bc[nt], acc[mt4][nt], 0, 0, 0);
      }
      if (s < 8) {
#pragma unroll
        for (int nt = 0; nt < 4; ++nt) Bc[nt] = Bn[nt];
      }
    }
    __syncthreads();                        // all MFMA reads of h1s done
    float* h2s = (float*)h1s;               // [oc][68]
#pragma unroll
    for (int u2 = 0; u2 < 2; ++u2) {
      const int py = wv * 2 + u2;
#pragma unroll
      for (int nt = 0; nt < 4; ++nt) {
        const f32x4 a = acc[2 * u2][nt], c = acc[2 * u2 + 1][nt];
        float2 pv;
        pv.x = fmaxf(fmaxf(fmaxf(a[0], a[1]), fmaxf(c[0], c[1])), 0.f);
        pv.y = fmaxf(fmaxf(fmaxf(a[2], a[3]), fmaxf(c[2], c[3])), 0.f);
        *(float2*)&h2s[(nt * 16 + n16) * 68 + py * 8 + 2 * q] = pv;
      }
    }
  }
  __syncthreads();
  {
    const float* h2s = (const float*)h1s;
    unsigned short* dst = h2b + (size_t)b * 4096;
#pragma unroll
    for (int j = 0; j < 2; ++j) {
      const int f = 8 * (t + 256 * j);          // flat k = oc*64+py*8+px
      const float* src = &h2s[(f >> 6) * 68 + (f & 63)];
      float4 v0 = *(const float4*)src;
      float4 v1 = *(const float4*)(src + 4);
      unsigned int p0 = pkbf(v0.x, v0.y);
      unsigned int p1 = pkbf(v0.z, v0.w);
      unsigned int p2 = pkbf(v1.x, v1.y);
      unsigned int p3 = pkbf(v1.z, v1.w);
      *(uint4*)(dst + f) = make_uint4(p0, p1, p2, p3);
    }
  }
}

// ---------------- K4: bucketed fc1, M=64 tile (bf16 MFMA, reg-prefetch) + relu + fc2 fp32 + aux ----------------
// M=16 -> M=64: each block now covers 64 samples but still reads its expert's full
// 1 MB fc1 weight slab once -> 4x less L2 weight traffic (256->64 MB actual) and 4x
// more MFMA per stage/sync. Wave split over oc unchanged (weight loads/wave/chunk
// identical); per-(sample,oc) MFMA chain identical (kc asc, ks asc) -> bit-identical.
__global__ __launch_bounds__(256) void k_fc(const unsigned short* __restrict__ h2b,
    const unsigned short* __restrict__ w1r, const float* __restrict__ b1g,
    const float* __restrict__ w2g, const float* __restrict__ b2g,
    const int* __restrict__ counts, const int* __restrict__ order,
    const float* __restrict__ ew, const float* __restrict__ psum,
    float* __restrict__ outp) {
  const int bid = blockIdx.x;
  if (bid == 0 && threadIdx.x == 0) {        // aux loss (before any early-exit)
    float a = 0.f;
#pragma unroll
    for (int j = 0; j < 4; ++j) {
      const float mp = psum[j] * (1.f / 4096.f) - 0.25f;
      a += mp * mp;
    }
    outp[57344] = a * 0.25f;
  }
  const int e = bid >> 6, tile = bid & 63;   // 4 experts x 64 tiles of 64 samples
  const int n = counts[e];
  const int base = tile * 64;
  if (base >= n) return;
  const int t = threadIdx.x;
  __shared__ int sb[64];
  __shared__ float wgt[64];
  // union: As[64][280] u16 (35840 B, K-loop) / f1s[64*132] f32 (33792 B, epilogue)
  __shared__ __align__(16) unsigned char fsm[35840];
  unsigned short (*const As)[280] = (unsigned short (*)[280])fsm;
  float* const f1s = (float*)fsm;
  if (t < 64) {
    const int idx = base + t;
    const int s = order[e * B_N + ((idx < n) ? idx : base)];
    sb[t] = s; wgt[t] = ew[s];
  }
  __syncthreads();
  const int lane = t & 63, wv = t >> 6;
  const int n16 = lane & 15, q = lane >> 4;
  const int oc0 = wv * 32 + n16;           // n-tile 2*wv
  const int oc1 = wv * 32 + 16 + n16;      // n-tile 2*wv+1
  const unsigned short* wb0 = w1r + ((size_t)(e * 128 + oc0)) * 4096 + q * 8;
  const unsigned short* wb1 = w1r + ((size_t)(e * 128 + oc1)) * 4096 + q * 8;
  f32x4 acc0[4], acc1[4];
#pragma unroll
  for (int mt = 0; mt < 4; ++mt) {
    acc0[mt][0] = 0.f; acc0[mt][1] = 0.f; acc0[mt][2] = 0.f; acc0[mt][3] = 0.f;
    acc1[mt][0] = 0.f; acc1[mt][1] = 0.f; acc1[mt][2] = 0.f; acc1[mt][3] = 0.f;
  }
  // staging: 4 threads per row; thread covers 8 consecutive uint4 (128 u16 run)
  const int srow = t >> 2, scseg = t & 3;                   // row 0..63, seg 0..3
  const unsigned short* asrc = h2b + (size_t)sb[srow] * 4096 + scseg * 64;
  uint4 r0[8];
#pragma unroll
  for (int j = 0; j < 8; ++j) r0[j] = *(const uint4*)(asrc + j * 8);   // prefetch kc=0
  for (int kc = 0; kc < 4096; kc += 256) {
#pragma unroll
    for (int j = 0; j < 8; ++j) *(uint4*)&As[srow][scseg * 64 + j * 8] = r0[j];
    __syncthreads();
    if (kc + 256 < 4096) {                                 // prefetch next chunk (overlaps MFMA)
#pragma unroll
      for (int j = 0; j < 8; ++j) r0[j] = *(const uint4*)(asrc + (kc + 256) + j * 8);
    }
#pragma unroll
    for (int ks = 0; ks < 8; ++ks) {
      const short8 bf0 = *(const short8*)(wb0 + kc + ks * 32);       // B[k][n=oc0]
      const short8 bf1 = *(const short8*)(wb1 + kc + ks * 32);
#pragma unroll
      for (int mt = 0; mt < 4; ++mt) {
        const short8 af = *(const short8*)&As[mt * 16 + n16][ks * 32 + q * 8];  // A[m][k]
        acc0[mt] = __builtin_amdgcn_mfma_f32_16x16x32_bf16(af, bf0, acc0[mt], 0, 0, 0);
        acc1[mt] = __builtin_amdgcn_mfma_f32_16x16x32_bf16(af, bf1, acc1[mt], 0, 0, 0);
      }
    }
    __syncthreads();
  }
  // C layout per m-tile: row m = mt*16 + q*4 + r (sample), col = n16 (oc)
  const float* b1 = b1g + e * 128;
  const float bb0 = b1[oc0], bb1 = b1[oc1];
#pragma unroll
  for (int mt = 0; mt < 4; ++mt)
#pragma unroll
    for (int r = 0; r < 4; ++r) {
      const int m = mt * 16 + q * 4 + r;
      f1s[m * 132 + oc0] = fmaxf(acc0[mt][r] + bb0, 0.f);
      f1s[m * 132 + oc1] = fmaxf(acc1[mt][r] + bb1, 0.f);
    }
  __syncthreads();
  int m = n - base; if (m > 64) m = 64;
  for (int flat = t; flat < 640; flat += 256) {
    const int r = flat / 10, o = flat - r * 10;
    if (r < m) {
      const float* w2 = w2g + (e * 10 + o) * 128;
      float s = b2g[e * 10 + o];
#pragma unroll 8
      for (int c = 0; c < 128; ++c) s += f1s[r * 132 + c] * w2[c];
      outp[(size_t)sb[r] * 10 + o] = s * wgt[r];
    }
  }
}

extern "C" void kernel_launch(void* const* d_in, const int* in_sizes, int n_in,
                              void* d_out, int out_size, void* d_ws, size_t ws_size,
                              hipStream_t stream) {
  const float* x        = (const float*)d_in[0];
  const float* gw_conv  = (const float*)d_in[1];
  const float* gb_conv  = (const float*)d_in[2];
  const float* gw_fc    = (const float*)d_in[3];
  const float* gb_fc    = (const float*)d_in[4];
  const float* ew_conv1 = (const float*)d_in[5];
  const float* eb_conv1 = (const float*)d_in[6];
  const float* ew_conv2 = (const float*)d_in[7];
  const float* eb_conv2 = (const float*)d_in[8];
  const float* ew_fc1   = (const float*)d_in[9];
  const float* eb_fc1   = (const float*)d_in[10];
  const float* ew_fc2   = (const float*)d_in[11];
  const float* eb_fc2   = (const float*)d_in[12];
  float* out = (float*)d_out;
  float* ws  = (float*)d_ws;

  unsigned short* h2b = (unsigned short*)(ws + H2B_OFF);
  float* pooled = ws + POOLED_OFF;
  int*   eidx   = (int*)(ws + EIDX_OFF);
  float* ew     = ws + EW_OFF;
  int*   order  = (int*)(ws + ORDER_OFF);
  int*   counts = (int*)(ws + CNT_OFF);
  float* psum   = ws + PSUM_OFF;
  unsigned short* w2r = (unsigned short*)(ws + W2R_OFF);
  unsigned short* w1r = (unsigned short*)(ws + W1R_OFF);
  unsigned short* w1c = (unsigned short*)(ws + W1C_OFF);

  k_front<<<6448, 256, 0, stream>>>(x, gw_conv, gb_conv, pooled,
                                    ew_fc1, w1r, ew_conv2, w2r, ew_conv1, w1c, counts);
  k_router_fc<<<16, 256, 0, stream>>>(pooled, gw_fc, gb_fc, out + 40960, eidx, ew,
                                      counts, order, psum);
  k_experts_conv<<<4096, 256, 0, stream>>>(x, w1c, eb_conv1, w2r, eb_conv2,
                                           eidx, h2b);
  k_fc<<<256, 256, 0, stream>>>(h2b, w1r, eb_fc1, ew_fc2, eb_fc2,
                                counts, order, ew, psum, out);
}

// Round 6
// 249.874 us; speedup vs baseline: 1.4529x; 1.4284x over previous
//
#include <hip/hip_runtime.h>
#include <hip/hip_bf16.h>
#include <cstdint>
#include <cstddef>

#define B_N 4096
typedef short short8 __attribute__((ext_vector_type(8)));
typedef float f32x4 __attribute__((ext_vector_type(4)));

// ws layout (float units)
static constexpr size_t H2B_OFF    = 0;                                  // 4096*4096 ushort
static constexpr size_t POOLED_OFF = 8388608;                            // B*16 f (unused now)
static constexpr size_t EIDX_OFF   = POOLED_OFF + (size_t)B_N * 16;      // B int (unused now)
static constexpr size_t EW_OFF     = EIDX_OFF + B_N;                     // B f
static constexpr size_t ORDER_OFF  = EW_OFF + B_N;                       // 4*B int
static constexpr size_t CNT_OFF    = ORDER_OFF + (size_t)4 * B_N;        // 4 int (+4 legacy psum)
static constexpr size_t PSUM_OFF   = CNT_OFF + 4;                        // 4 f (legacy, zeroed only)
static constexpr size_t W2R_OFF    = PSUM_OFF + 4;                       // 73728 ushort = 36864 f
static constexpr size_t W1R_OFF    = W2R_OFF + 36864;                    // 2097152 ushort = 1048576 f
static constexpr size_t W1C_OFF    = W1R_OFF + 1048576;                  // 4096 ushort = 2048 f

__device__ __forceinline__ unsigned int f2bf(float f) {
  unsigned int u = __float_as_uint(f);
  return (u + 0x7fffu + ((u >> 16) & 1u)) >> 16;   // RNE bf16
}
__device__ __forceinline__ unsigned int pkbf(float lo, float hi) {
  float2 f; f.x = lo; f.y = hi;
  __hip_bfloat162 b = __float22bfloat162_rn(f);     // v_cvt_pk_bf16_f32
  union { __hip_bfloat162 b; unsigned u; } c; c.b = b; return c.u;
}

// ---------------- K1: weight repacks ONLY (router fused into K3) ----------------
__global__ __launch_bounds__(256) void k_front(
    const float* __restrict__ wfc1, unsigned short* __restrict__ w1r,
    const float* __restrict__ wc2, unsigned short* __restrict__ w2r,
    const float* __restrict__ wc1, unsigned short* __restrict__ w1c,
    int* __restrict__ counts) {
  const int rb = blockIdx.x, t = threadIdx.x;
  if (rb < 2048) {
    const int i = rb * 256 + t;                    // float4 index
    const float4 v = ((const float4*)wfc1)[i];
    ushort4 u;
    u.x = (unsigned short)f2bf(v.x); u.y = (unsigned short)f2bf(v.y);
    u.z = (unsigned short)f2bf(v.z); u.w = (unsigned short)f2bf(v.w);
    *(ushort4*)(w1r + 4 * (size_t)i) = u;
  } else if (rb < 2336) {
    if (rb == 2048 && t < 8) counts[t] = 0;        // counts[4] (+legacy psum[4])
    const int i = (rb - 2048) * 256 + t;
    if (i < 4 * 9 * 64 * 32) {
      const int ic = i & 31, j = i >> 5;
      const int oc = j & 63, j2 = j >> 6;
      const int s = j2 % 9, e = j2 / 9;
      w2r[i] = (unsigned short)f2bf(wc2[(((size_t)e * 64 + oc) * 32 + ic) * 9 + s]);
    }
  } else {
    const int i = (rb - 2336) * 256 + t;           // [0, 4096)
    if (i < 4096) {
      const int j = i & 7, n16 = (i >> 3) & 15, q = (i >> 7) & 3, nt = (i >> 9) & 1, e = i >> 10;
      const int k = q * 8 + j;
      float v = 0.f;
      if (k < 27) {
        const int ky = k / 9, c = k % 9, kx = c / 3, ic = c % 3;
        v = wc1[((e * 32 + nt * 16 + n16) * 3 + ic) * 9 + ky * 3 + kx];
      }
      w1c[i] = (unsigned short)f2bf(v);
    }
  }
}

// ---- conv1 A-fragment gather from ic-interleaved fp32 image (packed bf16 cvt) ----
__device__ __forceinline__ short8 gather_a(const float* __restrict__ base,
                                           const int* goff, bool isq1, bool isq3) {
  const float a0 = base[goff[0]];
  float       a1 = base[goff[0] + 1];
  const float b0 = base[goff[1]], b1 = base[goff[1] + 1];
  const float c0 = base[goff[2]], c1 = base[goff[2] + 1];
  const float d0 = base[goff[3]], d1 = base[goff[3] + 1];
  a1 = isq1 ? base[102] : a1;          // patch: p=9 (row 1, c 0) for q==1 lanes
  union { unsigned u[4]; short8 s; } r;
  r.u[0] = pkbf(a0, a1);
  r.u[1] = pkbf(b0, isq3 ? 0.f : b1);  // p>=27 zero padding (q==3)
  r.u[2] = isq3 ? 0u : pkbf(c0, c1);
  r.u[3] = isq3 ? 0u : pkbf(d0, d1);
  return r.s;
}

// ---------------- K3: FUSED router (conv16+pool+fc+softmax+top1, verbatim arithmetic)
// + conv1 MFMA (im2col) -> h1 bf16 LDS -> conv2 MFMA -> h2 bf16 ----------------
// Router reads the SAME xpi staging conv1 uses (values bit-identical to the old
// k_front xpad path; FMA nesting / shuffle tree / 33-slot partials / 32-term final
// sum / softmax loops copied verbatim) -> routing decisions bit-identical.
// Conv body unchanged from the verified 69-us baseline: (256,3), reg floor ~148
// (incl 64 AGPR acc); caps <=128 spill (R1/R2/R4 evidence).
__global__ __launch_bounds__(256, 3) void k_experts_conv(const float* __restrict__ x,
    const float* __restrict__ gw, const float* __restrict__ gb,
    const float* __restrict__ gwfc, const float* __restrict__ gbfc,
    const unsigned short* __restrict__ w1c, const float* __restrict__ b1g,
    const unsigned short* __restrict__ w2r, const float* __restrict__ b2g,
    unsigned short* __restrict__ h2b, float* __restrict__ probs_out,
    float* __restrict__ ewt, int* __restrict__ counts, int* __restrict__ order) {
  __shared__ __align__(16) float xpi[3572];                  // [34 rows][34 cols][3 ic] +pad, 14288 B
  __shared__ __align__(16) unsigned short h1s[18 * 18 * 36]; // 23328 B, pixel stride 36 u16 (bank pad)
  __shared__ float red[16 * 33];                             // router partials, 2112 B
  __shared__ float pooled_s[16];
  __shared__ int es;
  const int b = blockIdx.x, t = threadIdx.x;
  {
    uint4 z4 = make_uint4(0, 0, 0, 0);
    uint4* z1 = (uint4*)h1s;
    for (int i = t; i < 1458; i += 256) z1[i] = z4;
    uint4* z2 = (uint4*)xpi;
    for (int i = t; i < 893; i += 256) z2[i] = z4;
  }
  __syncthreads();
  const float4* x4 = (const float4*)(x + (size_t)b * 3072);
  for (int i = t; i < 768; i += 256) {
    float4 v = x4[i];
    int flat = i * 4, ic = flat >> 10, rem = flat & 1023, row = rem >> 5, col = rem & 31;
    float* d = &xpi[(row + 1) * 102 + (col + 1) * 3 + ic];
    d[0] = v.x; d[3] = v.y; d[6] = v.z; d[9] = v.w;
  }
  __syncthreads();
  // ---- fused router: values from xpi (identical bits to old xpad staging) ----
  {
    const int ty = t >> 4, tx = t & 15;
    float win[3][4][4];
#pragma unroll
    for (int ic = 0; ic < 3; ++ic)
#pragma unroll
    for (int rr = 0; rr < 4; ++rr) {
      const float* p = &xpi[(2 * ty + rr) * 102 + (2 * tx) * 3 + ic];
      win[ic][rr][0] = p[0]; win[ic][rr][1] = p[3];
      win[ic][rr][2] = p[6]; win[ic][rr][3] = p[9];
    }
    float sums[16];
#pragma unroll
    for (int oc = 0; oc < 16; ++oc) {
      const float bias = gb[oc];
      float a00 = bias, a01 = bias, a10 = bias, a11 = bias;
#pragma unroll
      for (int ic = 0; ic < 3; ++ic)
#pragma unroll
      for (int ky = 0; ky < 3; ++ky)
#pragma unroll
      for (int kx = 0; kx < 3; ++kx) {
        const float wv2 = gw[oc * 27 + ic * 9 + ky * 3 + kx];   // block-uniform -> SGPR
        a00 += wv2 * win[ic][ky][kx];     a01 += wv2 * win[ic][ky][kx + 1];
        a10 += wv2 * win[ic][ky + 1][kx]; a11 += wv2 * win[ic][ky + 1][kx + 1];
      }
      sums[oc] = fmaxf(a00, 0.f) + fmaxf(a01, 0.f) + fmaxf(a10, 0.f) + fmaxf(a11, 0.f);
    }
    const int rl = t & 63, wid = t >> 6;
#pragma unroll
    for (int oc = 0; oc < 16; ++oc) {
      float s = sums[oc];
      s += __shfl_xor(s, 1);
      s += __shfl_xor(s, 2);
      s += __shfl_xor(s, 4);
      sums[oc] = s;
    }
    if ((rl & 7) == 0) {
      const int slot = wid * 8 + (rl >> 3);
#pragma unroll
      for (int oc = 0; oc < 16; ++oc) red[oc * 33 + slot] = sums[oc];
    }
    __syncthreads();
    if (t < 16) {
      float s = 0.f;
#pragma unroll
      for (int i = 0; i < 32; ++i) s += red[t * 33 + i];
      pooled_s[t] = s * (1.f / 1024.f);
    }
    __syncthreads();
    if (t == 0) {   // verbatim k_router_fc per-sample math
      float l[4];
#pragma unroll
      for (int j = 0; j < 4; ++j) {
        float s = gbfc[j];
#pragma unroll
        for (int i = 0; i < 16; ++i) s += pooled_s[i] * gwfc[j * 16 + i];
        l[j] = s;
      }
      const float mx = fmaxf(fmaxf(l[0], l[1]), fmaxf(l[2], l[3]));
      float ex[4], ssum = 0.f;
#pragma unroll
      for (int j = 0; j < 4; ++j) { ex[j] = expf(l[j] - mx); ssum += ex[j]; }
      const float inv = 1.f / ssum;
      float p[4];
#pragma unroll
      for (int j = 0; j < 4; ++j) p[j] = ex[j] * inv;
      *(float4*)(probs_out + (size_t)b * 4) = make_float4(p[0], p[1], p[2], p[3]);
      int em = 0; float pm = p[0];
#pragma unroll
      for (int j = 1; j < 4; ++j) if (p[j] > pm) { pm = p[j]; em = j; }
      ewt[b] = pm;
      const int slot = atomicAdd(&counts[em], 1);
      order[em * B_N + slot] = b;
      es = em;
    }
    __syncthreads();
  }
  const int e = __builtin_amdgcn_readfirstlane(es);
  const int lane = t & 63, wv = t >> 6;
  const int n16 = lane & 15, q = lane >> 4;
  // ---- conv1: MFMA 16x16x32, K=27(+pad), M=pixel col, N=32 oc ----
  {
    const bool isq1 = (q == 1), isq3 = (q == 3);
    const short8 wb0 = *(const short8*)(w1c + (((e * 2 + 0) * 4 + q) * 16 + n16) * 8);
    const short8 wb1 = *(const short8*)(w1c + (((e * 2 + 1) * 4 + q) * 16 + n16) * 8);
    const float bias0 = b1g[e * 32 + n16];
    const float bias1 = b1g[e * 32 + 16 + n16];
    int goff[4];
#pragma unroll
    for (int t4 = 0; t4 < 4; ++t4) {
      const int p0 = q * 8 + 2 * t4;
      const int r = (p0 * 939) >> 13;        // p0/9 for p0<32
      goff[t4] = r * 102 + (p0 - 9 * r);
    }
    for (int pid = 0; pid < 8; ++pid) {
      const int pairid = wv * 8 + pid;
      const int yp = pairid >> 1, xh = pairid & 1;
      const float* baseA = &xpi[(2 * yp) * 102 + (xh * 16 + n16) * 3];
      const short8 afA = gather_a(baseA, goff, isq1, isq3);
      const short8 afB = gather_a(baseA + 102, goff, isq1, isq3);
      f32x4 aA0 = {bias0, bias0, bias0, bias0}, aA1 = {bias1, bias1, bias1, bias1};
      f32x4 aB0 = aA0, aB1 = aA1;
      aA0 = __builtin_amdgcn_mfma_f32_16x16x32_bf16(afA, wb0, aA0, 0, 0, 0);
      aA1 = __builtin_amdgcn_mfma_f32_16x16x32_bf16(afA, wb1, aA1, 0, 0, 0);
      aB0 = __builtin_amdgcn_mfma_f32_16x16x32_bf16(afB, wb0, aB0, 0, 0, 0);
      aB1 = __builtin_amdgcn_mfma_f32_16x16x32_bf16(afB, wb1, aB1, 0, 0, 0);
      // 2x2 maxpool + relu -> h1s[pix][ic] bf16 (pixel stride 36)
      const int px = xh * 8 + 2 * q;
      unsigned short* hw = &h1s[((yp + 1) * 18 + (px + 1)) * 36];
      const float p00 = fmaxf(fmaxf(fmaxf(aA0[0], aA0[1]), fmaxf(aB0[0], aB0[1])), 0.f);
      const float p01 = fmaxf(fmaxf(fmaxf(aA0[2], aA0[3]), fmaxf(aB0[2], aB0[3])), 0.f);
      const float p10 = fmaxf(fmaxf(fmaxf(aA1[0], aA1[1]), fmaxf(aB1[0], aB1[1])), 0.f);
      const float p11 = fmaxf(fmaxf(fmaxf(aA1[2], aA1[3]), fmaxf(aB1[2], aB1[3])), 0.f);
      hw[n16]           = (unsigned short)f2bf(p00);
      hw[16 + n16]      = (unsigned short)f2bf(p10);
      hw[36 + n16]      = (unsigned short)f2bf(p01);
      hw[36 + 16 + n16] = (unsigned short)f2bf(p11);
    }
  }
  __syncthreads();
  // ---- conv2: wave = 4 rows x all 64 oc; B streamed from global (L2) with prefetch ----
  {
    const unsigned short* wbase = w2r + (size_t)e * 18432 + n16 * 32 + q * 8;
    float bz[4];
#pragma unroll
    for (int nt = 0; nt < 4; ++nt) bz[nt] = b2g[e * 64 + nt * 16 + n16];
    f32x4 acc[4][4];
#pragma unroll
    for (int mt4 = 0; mt4 < 4; ++mt4)
#pragma unroll
      for (int nt = 0; nt < 4; ++nt) {
        acc[mt4][nt][0] = bz[nt]; acc[mt4][nt][1] = bz[nt];
        acc[mt4][nt][2] = bz[nt]; acc[mt4][nt][3] = bz[nt];
      }
    short8 Bc[4];
#pragma unroll
    for (int nt = 0; nt < 4; ++nt) Bc[nt] = *(const short8*)(wbase + nt * 512);
#pragma unroll
    for (int s = 0; s < 9; ++s) {
      const int ky = s / 3, kx = s % 3;
      short8 Bn[4];
      if (s < 8) {
#pragma unroll
        for (int nt = 0; nt < 4; ++nt)
          Bn[nt] = *(const short8*)(wbase + (s + 1) * 2048 + nt * 512);
      }
#pragma unroll
      for (int mt4 = 0; mt4 < 4; ++mt4) {
        const int mt = wv * 4 + mt4;
        const short8 af = *(const short8*)&h1s[((mt + ky) * 18 + n16 + kx) * 36 + q * 8];
#pragma unroll
        for (int nt = 0; nt < 4; ++nt)
          acc[mt4][nt] = __builtin_amdgcn_mfma_f32_16x16x32_bf16(af, Bc[nt], acc[mt4][nt], 0, 0, 0);
      }
      if (s < 8) {
#pragma unroll
        for (int nt = 0; nt < 4; ++nt) Bc[nt] = Bn[nt];
      }
    }
    __syncthreads();                        // all MFMA reads of h1s done
    float* h2s = (float*)h1s;               // [oc][68]
#pragma unroll
    for (int u2 = 0; u2 < 2; ++u2) {
      const int py = wv * 2 + u2;
#pragma unroll
      for (int nt = 0; nt < 4; ++nt) {
        const f32x4 a = acc[2 * u2][nt], c = acc[2 * u2 + 1][nt];
        float2 pv;
        pv.x = fmaxf(fmaxf(fmaxf(a[0], a[1]), fmaxf(c[0], c[1])), 0.f);
        pv.y = fmaxf(fmaxf(fmaxf(a[2], a[3]), fmaxf(c[2], c[3])), 0.f);
        *(float2*)&h2s[(nt * 16 + n16) * 68 + py * 8 + 2 * q] = pv;
      }
    }
  }
  __syncthreads();
  {
    const float* h2s = (const float*)h1s;
    unsigned short* dst = h2b + (size_t)b * 4096;
#pragma unroll
    for (int j = 0; j < 2; ++j) {
      const int f = 8 * (t + 256 * j);          // flat k = oc*64+py*8+px
      const float* src = &h2s[(f >> 6) * 68 + (f & 63)];
      float4 v0 = *(const float4*)src;
      float4 v1 = *(const float4*)(src + 4);
      unsigned int p0 = pkbf(v0.x, v0.y);
      unsigned int p1 = pkbf(v0.z, v0.w);
      unsigned int p2 = pkbf(v1.x, v1.y);
      unsigned int p3 = pkbf(v1.z, v1.w);
      *(uint4*)(dst + f) = make_uint4(p0, p1, p2, p3);
    }
  }
}

// ---------------- K4: bucketed fc1 (M=16, bf16 MFMA, reg-prefetch) + relu + fc2 fp32
// + aux (deterministic reduce of probs_out; replaces psum atomics) ----------------
__global__ __launch_bounds__(256) void k_fc(const unsigned short* __restrict__ h2b,
    const unsigned short* __restrict__ w1r, const float* __restrict__ b1g,
    const float* __restrict__ w2g, const float* __restrict__ b2g,
    const int* __restrict__ counts, const int* __restrict__ order,
    const float* __restrict__ ew, float* __restrict__ outp) {
  const int bid = blockIdx.x;
  const int t = threadIdx.x;
  if (bid == 0) {                            // aux loss (before any early-exit)
    const float* pr = outp + 40960;          // probs_out
    float s0 = 0.f, s1 = 0.f, s2 = 0.f, s3 = 0.f;
    for (int i = t; i < 4096; i += 256) {
      const float4 v = *(const float4*)(pr + (size_t)i * 4);
      s0 += v.x; s1 += v.y; s2 += v.z; s3 += v.w;
    }
#pragma unroll
    for (int k = 1; k < 64; k <<= 1) {
      s0 += __shfl_xor(s0, k); s1 += __shfl_xor(s1, k);
      s2 += __shfl_xor(s2, k); s3 += __shfl_xor(s3, k);
    }
    __shared__ float ax[4][4];
    if ((t & 63) == 0) {
      const int w = t >> 6;
      ax[w][0] = s0; ax[w][1] = s1; ax[w][2] = s2; ax[w][3] = s3;
    }
    __syncthreads();
    if (t == 0) {
      float a = 0.f;
#pragma unroll
      for (int j = 0; j < 4; ++j) {
        const float mp = (ax[0][j] + ax[1][j] + ax[2][j] + ax[3][j]) * (1.f / 4096.f) - 0.25f;
        a += mp * mp;
      }
      outp[57344] = a * 0.25f;
    }
  }
  const int e = bid >> 8, tile = bid & 255;
  const int n = counts[e];
  const int base = tile * 16;
  if (base >= n) return;
  __shared__ int sb[16];
  __shared__ float wgt[16];
  __shared__ __align__(16) unsigned short As[16][280];   // 16 x 256 k, stride 280 (bank-clean)
  __shared__ float f1s[16 * 132];
  if (t < 16) {
    const int idx = base + t;
    const int s = order[e * B_N + ((idx < n) ? idx : base)];
    sb[t] = s; wgt[t] = ew[s];
  }
  __syncthreads();
  const int lane = t & 63, wv = t >> 6;
  const int n16 = lane & 15, q = lane >> 4;
  const int oc0 = wv * 32 + n16;           // n-tile 2*wv
  const int oc1 = wv * 32 + 16 + n16;      // n-tile 2*wv+1
  const unsigned short* wb0 = w1r + ((size_t)(e * 128 + oc0)) * 4096 + q * 8;
  const unsigned short* wb1 = w1r + ((size_t)(e * 128 + oc1)) * 4096 + q * 8;
  f32x4 acc0 = {0.f, 0.f, 0.f, 0.f}, acc1 = {0.f, 0.f, 0.f, 0.f};
  const int ldrow = t >> 4, ldseg = t & 15;
  const unsigned short* asrc = h2b + (size_t)sb[ldrow] * 4096;
  uint4 r0 = *(const uint4*)(asrc + ldseg * 8);            // prefetch kc=0
  uint4 r1 = *(const uint4*)(asrc + (ldseg + 16) * 8);
  for (int kc = 0; kc < 4096; kc += 256) {
    *(uint4*)&As[ldrow][ldseg * 8] = r0;
    *(uint4*)&As[ldrow][(ldseg + 16) * 8] = r1;
    __syncthreads();
    if (kc + 256 < 4096) {                                 // prefetch next chunk (overlaps MFMA)
      r0 = *(const uint4*)(asrc + (kc + 256) + ldseg * 8);
      r1 = *(const uint4*)(asrc + (kc + 256) + (ldseg + 16) * 8);
    }
#pragma unroll
    for (int ks = 0; ks < 8; ++ks) {
      const short8 af = *(const short8*)&As[n16][ks * 32 + q * 8];   // A[m=n16][k]
      const short8 bf0 = *(const short8*)(wb0 + kc + ks * 32);       // B[k][n=oc0]
      const short8 bf1 = *(const short8*)(wb1 + kc + ks * 32);
      acc0 = __builtin_amdgcn_mfma_f32_16x16x32_bf16(af, bf0, acc0, 0, 0, 0);
      acc1 = __builtin_amdgcn_mfma_f32_16x16x32_bf16(af, bf1, acc1, 0, 0, 0);
    }
    __syncthreads();
  }
  // C layout: row m = q*4+r (sample), col = n16 (oc)
  const float* b1 = b1g + e * 128;
  const float bb0 = b1[oc0], bb1 = b1[oc1];
#pragma unroll
  for (int r = 0; r < 4; ++r) {
    const int m = q * 4 + r;
    f1s[m * 132 + oc0] = fmaxf(acc0[r] + bb0, 0.f);
    f1s[m * 132 + oc1] = fmaxf(acc1[r] + bb1, 0.f);
  }
  __syncthreads();
  int m = n - base; if (m > 16) m = 16;
  if (t < 160) {
    const int r = t / 10, o = t - r * 10;
    if (r < m) {
      const float* w2 = w2g + (e * 10 + o) * 128;
      float s = b2g[e * 10 + o];
#pragma unroll 8
      for (int c = 0; c < 128; ++c) s += f1s[r * 132 + c] * w2[c];
      outp[(size_t)sb[r] * 10 + o] = s * wgt[r];
    }
  }
}

extern "C" void kernel_launch(void* const* d_in, const int* in_sizes, int n_in,
                              void* d_out, int out_size, void* d_ws, size_t ws_size,
                              hipStream_t stream) {
  const float* x        = (const float*)d_in[0];
  const float* gw_conv  = (const float*)d_in[1];
  const float* gb_conv  = (const float*)d_in[2];
  const float* gw_fc    = (const float*)d_in[3];
  const float* gb_fc    = (const float*)d_in[4];
  const float* ew_conv1 = (const float*)d_in[5];
  const float* eb_conv1 = (const float*)d_in[6];
  const float* ew_conv2 = (const float*)d_in[7];
  const float* eb_conv2 = (const float*)d_in[8];
  const float* ew_fc1   = (const float*)d_in[9];
  const float* eb_fc1   = (const float*)d_in[10];
  const float* ew_fc2   = (const float*)d_in[11];
  const float* eb_fc2   = (const float*)d_in[12];
  float* out = (float*)d_out;
  float* ws  = (float*)d_ws;

  unsigned short* h2b = (unsigned short*)(ws + H2B_OFF);
  float* ew     = ws + EW_OFF;
  int*   order  = (int*)(ws + ORDER_OFF);
  int*   counts = (int*)(ws + CNT_OFF);
  unsigned short* w2r = (unsigned short*)(ws + W2R_OFF);
  unsigned short* w1r = (unsigned short*)(ws + W1R_OFF);
  unsigned short* w1c = (unsigned short*)(ws + W1C_OFF);

  k_front<<<2352, 256, 0, stream>>>(ew_fc1, w1r, ew_conv2, w2r, ew_conv1, w1c, counts);
  k_experts_conv<<<4096, 256, 0, stream>>>(x, gw_conv, gb_conv, gw_fc, gb_fc,
                                           w1c, eb_conv1, w2r, eb_conv2, h2b,
                                           out + 40960, ew, counts, order);
  k_fc<<<1024, 256, 0, stream>>>(h2b, w1r, eb_fc1, ew_fc2, eb_fc2,
                                 counts, order, ew, out);
}

// Round 7
// 246.767 us; speedup vs baseline: 1.4712x; 1.0126x over previous
//
#include <hip/hip_runtime.h>
#include <hip/hip_bf16.h>
#include <cstdint>
#include <cstddef>

#define B_N 4096
typedef short short8 __attribute__((ext_vector_type(8)));
typedef float f32x4 __attribute__((ext_vector_type(4)));
typedef float f32x2 __attribute__((ext_vector_type(2)));

// ws layout (float units)
static constexpr size_t H2B_OFF    = 0;                                  // 4096*4096 ushort
static constexpr size_t POOLED_OFF = 8388608;                            // B*16 f (unused now)
static constexpr size_t EIDX_OFF   = POOLED_OFF + (size_t)B_N * 16;      // B int (unused now)
static constexpr size_t EW_OFF     = EIDX_OFF + B_N;                     // B f
static constexpr size_t ORDER_OFF  = EW_OFF + B_N;                       // 4*B int
static constexpr size_t CNT_OFF    = ORDER_OFF + (size_t)4 * B_N;        // 4 int (+4 legacy psum)
static constexpr size_t PSUM_OFF   = CNT_OFF + 4;                        // 4 f (legacy, zeroed only)
static constexpr size_t W2R_OFF    = PSUM_OFF + 4;                       // 73728 ushort = 36864 f
static constexpr size_t W1R_OFF    = W2R_OFF + 36864;                    // 2097152 ushort = 1048576 f
static constexpr size_t W1C_OFF    = W1R_OFF + 1048576;                  // 4096 ushort = 2048 f

__device__ __forceinline__ unsigned int f2bf(float f) {
  unsigned int u = __float_as_uint(f);
  return (u + 0x7fffu + ((u >> 16) & 1u)) >> 16;   // RNE bf16
}
__device__ __forceinline__ unsigned int pkbf(float lo, float hi) {
  float2 f; f.x = lo; f.y = hi;
  __hip_bfloat162 b = __float22bfloat162_rn(f);     // v_cvt_pk_bf16_f32
  union { __hip_bfloat162 b; unsigned u; } c; c.b = b; return c.u;
}

// ---------------- K1: weight repacks ONLY (router fused into K3) ----------------
__global__ __launch_bounds__(256) void k_front(
    const float* __restrict__ wfc1, unsigned short* __restrict__ w1r,
    const float* __restrict__ wc2, unsigned short* __restrict__ w2r,
    const float* __restrict__ wc1, unsigned short* __restrict__ w1c,
    int* __restrict__ counts) {
  const int rb = blockIdx.x, t = threadIdx.x;
  if (rb < 2048) {
    const int i = rb * 256 + t;                    // float4 index
    const float4 v = ((const float4*)wfc1)[i];
    ushort4 u;
    u.x = (unsigned short)f2bf(v.x); u.y = (unsigned short)f2bf(v.y);
    u.z = (unsigned short)f2bf(v.z); u.w = (unsigned short)f2bf(v.w);
    *(ushort4*)(w1r + 4 * (size_t)i) = u;
  } else if (rb < 2336) {
    if (rb == 2048 && t < 8) counts[t] = 0;        // counts[4] (+legacy psum[4])
    const int i = (rb - 2048) * 256 + t;
    if (i < 4 * 9 * 64 * 32) {
      const int ic = i & 31, j = i >> 5;
      const int oc = j & 63, j2 = j >> 6;
      const int s = j2 % 9, e = j2 / 9;
      w2r[i] = (unsigned short)f2bf(wc2[(((size_t)e * 64 + oc) * 32 + ic) * 9 + s]);
    }
  } else {
    const int i = (rb - 2336) * 256 + t;           // [0, 4096)
    if (i < 4096) {
      const int j = i & 7, n16 = (i >> 3) & 15, q = (i >> 7) & 3, nt = (i >> 9) & 1, e = i >> 10;
      const int k = q * 8 + j;
      float v = 0.f;
      if (k < 27) {
        const int ky = k / 9, c = k % 9, kx = c / 3, ic = c % 3;
        v = wc1[((e * 32 + nt * 16 + n16) * 3 + ic) * 9 + ky * 3 + kx];
      }
      w1c[i] = (unsigned short)f2bf(v);
    }
  }
}

// ---- conv1 A-fragment gather from ic-interleaved fp32 image (packed bf16 cvt) ----
__device__ __forceinline__ short8 gather_a(const float* __restrict__ base,
                                           const int* goff, bool isq1, bool isq3) {
  const float a0 = base[goff[0]];
  float       a1 = base[goff[0] + 1];
  const float b0 = base[goff[1]], b1 = base[goff[1] + 1];
  const float c0 = base[goff[2]], c1 = base[goff[2] + 1];
  const float d0 = base[goff[3]], d1 = base[goff[3] + 1];
  a1 = isq1 ? base[102] : a1;          // patch: p=9 (row 1, c 0) for q==1 lanes
  union { unsigned u[4]; short8 s; } r;
  r.u[0] = pkbf(a0, a1);
  r.u[1] = pkbf(b0, isq3 ? 0.f : b1);  // p>=27 zero padding (q==3)
  r.u[2] = isq3 ? 0u : pkbf(c0, c1);
  r.u[3] = isq3 ? 0u : pkbf(d0, d1);
  return r.s;
}

// ---------------- K3: FUSED router (conv16+pool+fc+softmax+top1) + conv1 MFMA ->
// h1 bf16 LDS -> conv2 MFMA -> h2 bf16 ----------------
// R6: fused router costs +57 us of VALU (1728 scalar v_fma_f32/thread). This round:
// packed-FP32 router -- accumulator pairs (a00,a01),(a10,a11) as f32x2 with
// __builtin_elementwise_fma -> v_pk_fma_f32 (full-rate on CDNA), 864 pk-FMA/thread.
// Element-wise rounding identical to scalar fma -> routing/probs bit-identical.
// Conv body unchanged from the verified 69-us baseline: (256,3), reg floor ~148
// (incl 64 AGPR acc); caps <=128 spill (R1/R2/R4 evidence).
__global__ __launch_bounds__(256, 3) void k_experts_conv(const float* __restrict__ x,
    const float* __restrict__ gw, const float* __restrict__ gb,
    const float* __restrict__ gwfc, const float* __restrict__ gbfc,
    const unsigned short* __restrict__ w1c, const float* __restrict__ b1g,
    const unsigned short* __restrict__ w2r, const float* __restrict__ b2g,
    unsigned short* __restrict__ h2b, float* __restrict__ probs_out,
    float* __restrict__ ewt, int* __restrict__ counts, int* __restrict__ order) {
  __shared__ __align__(16) float xpi[3572];                  // [34 rows][34 cols][3 ic] +pad, 14288 B
  __shared__ __align__(16) unsigned short h1s[18 * 18 * 36]; // 23328 B, pixel stride 36 u16 (bank pad)
  __shared__ float red[16 * 33];                             // router partials, 2112 B
  __shared__ float pooled_s[16];
  __shared__ int es;
  const int b = blockIdx.x, t = threadIdx.x;
  {
    uint4 z4 = make_uint4(0, 0, 0, 0);
    uint4* z1 = (uint4*)h1s;
    for (int i = t; i < 1458; i += 256) z1[i] = z4;
    uint4* z2 = (uint4*)xpi;
    for (int i = t; i < 893; i += 256) z2[i] = z4;
  }
  __syncthreads();
  const float4* x4 = (const float4*)(x + (size_t)b * 3072);
  for (int i = t; i < 768; i += 256) {
    float4 v = x4[i];
    int flat = i * 4, ic = flat >> 10, rem = flat & 1023, row = rem >> 5, col = rem & 31;
    float* d = &xpi[(row + 1) * 102 + (col + 1) * 3 + ic];
    d[0] = v.x; d[3] = v.y; d[6] = v.z; d[9] = v.w;
  }
  __syncthreads();
  // ---- fused router (packed fp32): values bit-identical to the scalar path ----
  {
    const int ty = t >> 4, tx = t & 15;
    // window pairs wp[ic][row][kx] = (win[row][kx], win[row][kx+1])
    f32x2 wp[3][4][3];
#pragma unroll
    for (int ic = 0; ic < 3; ++ic)
#pragma unroll
    for (int rr = 0; rr < 4; ++rr) {
      const float* p = &xpi[(2 * ty + rr) * 102 + (2 * tx) * 3 + ic];
      const float r0 = p[0], r1 = p[3], r2 = p[6], r3 = p[9];
      wp[ic][rr][0] = (f32x2){r0, r1};
      wp[ic][rr][1] = (f32x2){r1, r2};
      wp[ic][rr][2] = (f32x2){r2, r3};
    }
    float sums[16];
#pragma unroll
    for (int oc = 0; oc < 16; ++oc) {
      const float bias = gb[oc];
      f32x2 A0 = {bias, bias};   // (a00, a01)
      f32x2 A1 = {bias, bias};   // (a10, a11)
#pragma unroll
      for (int ic = 0; ic < 3; ++ic)
#pragma unroll
      for (int ky = 0; ky < 3; ++ky)
#pragma unroll
      for (int kx = 0; kx < 3; ++kx) {
        const float wv2 = gw[oc * 27 + ic * 9 + ky * 3 + kx];   // block-uniform -> SGPR
        const f32x2 ws = {wv2, wv2};
        A0 = __builtin_elementwise_fma(wp[ic][ky][kx], ws, A0);      // v_pk_fma_f32
        A1 = __builtin_elementwise_fma(wp[ic][ky + 1][kx], ws, A1);
      }
      sums[oc] = fmaxf(A0.x, 0.f) + fmaxf(A0.y, 0.f) + fmaxf(A1.x, 0.f) + fmaxf(A1.y, 0.f);
    }
    const int rl = t & 63, wid = t >> 6;
#pragma unroll
    for (int oc = 0; oc < 16; ++oc) {
      float s = sums[oc];
      s += __shfl_xor(s, 1);
      s += __shfl_xor(s, 2);
      s += __shfl_xor(s, 4);
      sums[oc] = s;
    }
    if ((rl & 7) == 0) {
      const int slot = wid * 8 + (rl >> 3);
#pragma unroll
      for (int oc = 0; oc < 16; ++oc) red[oc * 33 + slot] = sums[oc];
    }
    __syncthreads();
    if (t < 16) {
      float s = 0.f;
#pragma unroll
      for (int i = 0; i < 32; ++i) s += red[t * 33 + i];
      pooled_s[t] = s * (1.f / 1024.f);
    }
    __syncthreads();
    if (t == 0) {   // verbatim k_router_fc per-sample math
      float l[4];
#pragma unroll
      for (int j = 0; j < 4; ++j) {
        float s = gbfc[j];
#pragma unroll
        for (int i = 0; i < 16; ++i) s += pooled_s[i] * gwfc[j * 16 + i];
        l[j] = s;
      }
      const float mx = fmaxf(fmaxf(l[0], l[1]), fmaxf(l[2], l[3]));
      float ex[4], ssum = 0.f;
#pragma unroll
      for (int j = 0; j < 4; ++j) { ex[j] = expf(l[j] - mx); ssum += ex[j]; }
      const float inv = 1.f / ssum;
      float p[4];
#pragma unroll
      for (int j = 0; j < 4; ++j) p[j] = ex[j] * inv;
      *(float4*)(probs_out + (size_t)b * 4) = make_float4(p[0], p[1], p[2], p[3]);
      int em = 0; float pm = p[0];
#pragma unroll
      for (int j = 1; j < 4; ++j) if (p[j] > pm) { pm = p[j]; em = j; }
      ewt[b] = pm;
      const int slot = atomicAdd(&counts[em], 1);
      order[em * B_N + slot] = b;
      es = em;
    }
    __syncthreads();
  }
  const int e = __builtin_amdgcn_readfirstlane(es);
  const int lane = t & 63, wv = t >> 6;
  const int n16 = lane & 15, q = lane >> 4;
  // ---- conv1: MFMA 16x16x32, K=27(+pad), M=pixel col, N=32 oc ----
  {
    const bool isq1 = (q == 1), isq3 = (q == 3);
    const short8 wb0 = *(const short8*)(w1c + (((e * 2 + 0) * 4 + q) * 16 + n16) * 8);
    const short8 wb1 = *(const short8*)(w1c + (((e * 2 + 1) * 4 + q) * 16 + n16) * 8);
    const float bias0 = b1g[e * 32 + n16];
    const float bias1 = b1g[e * 32 + 16 + n16];
    int goff[4];
#pragma unroll
    for (int t4 = 0; t4 < 4; ++t4) {
      const int p0 = q * 8 + 2 * t4;
      const int r = (p0 * 939) >> 13;        // p0/9 for p0<32
      goff[t4] = r * 102 + (p0 - 9 * r);
    }
    for (int pid = 0; pid < 8; ++pid) {
      const int pairid = wv * 8 + pid;
      const int yp = pairid >> 1, xh = pairid & 1;
      const float* baseA = &xpi[(2 * yp) * 102 + (xh * 16 + n16) * 3];
      const short8 afA = gather_a(baseA, goff, isq1, isq3);
      const short8 afB = gather_a(baseA + 102, goff, isq1, isq3);
      f32x4 aA0 = {bias0, bias0, bias0, bias0}, aA1 = {bias1, bias1, bias1, bias1};
      f32x4 aB0 = aA0, aB1 = aA1;
      aA0 = __builtin_amdgcn_mfma_f32_16x16x32_bf16(afA, wb0, aA0, 0, 0, 0);
      aA1 = __builtin_amdgcn_mfma_f32_16x16x32_bf16(afA, wb1, aA1, 0, 0, 0);
      aB0 = __builtin_amdgcn_mfma_f32_16x16x32_bf16(afB, wb0, aB0, 0, 0, 0);
      aB1 = __builtin_amdgcn_mfma_f32_16x16x32_bf16(afB, wb1, aB1, 0, 0, 0);
      // 2x2 maxpool + relu -> h1s[pix][ic] bf16 (pixel stride 36)
      const int px = xh * 8 + 2 * q;
      unsigned short* hw = &h1s[((yp + 1) * 18 + (px + 1)) * 36];
      const float p00 = fmaxf(fmaxf(fmaxf(aA0[0], aA0[1]), fmaxf(aB0[0], aB0[1])), 0.f);
      const float p01 = fmaxf(fmaxf(fmaxf(aA0[2], aA0[3]), fmaxf(aB0[2], aB0[3])), 0.f);
      const float p10 = fmaxf(fmaxf(fmaxf(aA1[0], aA1[1]), fmaxf(aB1[0], aB1[1])), 0.f);
      const float p11 = fmaxf(fmaxf(fmaxf(aA1[2], aA1[3]), fmaxf(aB1[2], aB1[3])), 0.f);
      hw[n16]           = (unsigned short)f2bf(p00);
      hw[16 + n16]      = (unsigned short)f2bf(p10);
      hw[36 + n16]      = (unsigned short)f2bf(p01);
      hw[36 + 16 + n16] = (unsigned short)f2bf(p11);
    }
  }
  __syncthreads();
  // ---- conv2: wave = 4 rows x all 64 oc; B streamed from global (L2) with prefetch ----
  {
    const unsigned short* wbase = w2r + (size_t)e * 18432 + n16 * 32 + q * 8;
    float bz[4];
#pragma unroll
    for (int nt = 0; nt < 4; ++nt) bz[nt] = b2g[e * 64 + nt * 16 + n16];
    f32x4 acc[4][4];
#pragma unroll
    for (int mt4 = 0; mt4 < 4; ++mt4)
#pragma unroll
      for (int nt = 0; nt < 4; ++nt) {
        acc[mt4][nt][0] = bz[nt]; acc[mt4][nt][1] = bz[nt];
        acc[mt4][nt][2] = bz[nt]; acc[mt4][nt][3] = bz[nt];
      }
    short8 Bc[4];
#pragma unroll
    for (int nt = 0; nt < 4; ++nt) Bc[nt] = *(const short8*)(wbase + nt * 512);
#pragma unroll
    for (int s = 0; s < 9; ++s) {
      const int ky = s / 3, kx = s % 3;
      short8 Bn[4];
      if (s < 8) {
#pragma unroll
        for (int nt = 0; nt < 4; ++nt)
          Bn[nt] = *(const short8*)(wbase + (s + 1) * 2048 + nt * 512);
      }
#pragma unroll
      for (int mt4 = 0; mt4 < 4; ++mt4) {
        const int mt = wv * 4 + mt4;
        const short8 af = *(const short8*)&h1s[((mt + ky) * 18 + n16 + kx) * 36 + q * 8];
#pragma unroll
        for (int nt = 0; nt < 4; ++nt)
          acc[mt4][nt] = __builtin_amdgcn_mfma_f32_16x16x32_bf16(af, Bc[nt], acc[mt4][nt], 0, 0, 0);
      }
      if (s < 8) {
#pragma unroll
        for (int nt = 0; nt < 4; ++nt) Bc[nt] = Bn[nt];
      }
    }
    __syncthreads();                        // all MFMA reads of h1s done
    float* h2s = (float*)h1s;               // [oc][68]
#pragma unroll
    for (int u2 = 0; u2 < 2; ++u2) {
      const int py = wv * 2 + u2;
#pragma unroll
      for (int nt = 0; nt < 4; ++nt) {
        const f32x4 a = acc[2 * u2][nt], c = acc[2 * u2 + 1][nt];
        float2 pv;
        pv.x = fmaxf(fmaxf(fmaxf(a[0], a[1]), fmaxf(c[0], c[1])), 0.f);
        pv.y = fmaxf(fmaxf(fmaxf(a[2], a[3]), fmaxf(c[2], c[3])), 0.f);
        *(float2*)&h2s[(nt * 16 + n16) * 68 + py * 8 + 2 * q] = pv;
      }
    }
  }
  __syncthreads();
  {
    const float* h2s = (const float*)h1s;
    unsigned short* dst = h2b + (size_t)b * 4096;
#pragma unroll
    for (int j = 0; j < 2; ++j) {
      const int f = 8 * (t + 256 * j);          // flat k = oc*64+py*8+px
      const float* src = &h2s[(f >> 6) * 68 + (f & 63)];
      float4 v0 = *(const float4*)src;
      float4 v1 = *(const float4*)(src + 4);
      unsigned int p0 = pkbf(v0.x, v0.y);
      unsigned int p1 = pkbf(v0.z, v0.w);
      unsigned int p2 = pkbf(v1.x, v1.y);
      unsigned int p3 = pkbf(v1.z, v1.w);
      *(uint4*)(dst + f) = make_uint4(p0, p1, p2, p3);
    }
  }
}

// ---------------- K4: bucketed fc1 (M=16, bf16 MFMA, reg-prefetch) + relu + fc2 fp32
// + aux (deterministic reduce of probs_out) ----------------
__global__ __launch_bounds__(256) void k_fc(const unsigned short* __restrict__ h2b,
    const unsigned short* __restrict__ w1r, const float* __restrict__ b1g,
    const float* __restrict__ w2g, const float* __restrict__ b2g,
    const int* __restrict__ counts, const int* __restrict__ order,
    const float* __restrict__ ew, float* __restrict__ outp) {
  const int bid = blockIdx.x;
  const int t = threadIdx.x;
  if (bid == 0) {                            // aux loss (before any early-exit)
    const float* pr = outp + 40960;          // probs_out
    float s0 = 0.f, s1 = 0.f, s2 = 0.f, s3 = 0.f;
    for (int i = t; i < 4096; i += 256) {
      const float4 v = *(const float4*)(pr + (size_t)i * 4);
      s0 += v.x; s1 += v.y; s2 += v.z; s3 += v.w;
    }
#pragma unroll
    for (int k = 1; k < 64; k <<= 1) {
      s0 += __shfl_xor(s0, k); s1 += __shfl_xor(s1, k);
      s2 += __shfl_xor(s2, k); s3 += __shfl_xor(s3, k);
    }
    __shared__ float ax[4][4];
    if ((t & 63) == 0) {
      const int w = t >> 6;
      ax[w][0] = s0; ax[w][1] = s1; ax[w][2] = s2; ax[w][3] = s3;
    }
    __syncthreads();
    if (t == 0) {
      float a = 0.f;
#pragma unroll
      for (int j = 0; j < 4; ++j) {
        const float mp = (ax[0][j] + ax[1][j] + ax[2][j] + ax[3][j]) * (1.f / 4096.f) - 0.25f;
        a += mp * mp;
      }
      outp[57344] = a * 0.25f;
    }
  }
  const int e = bid >> 8, tile = bid & 255;
  const int n = counts[e];
  const int base = tile * 16;
  if (base >= n) return;
  __shared__ int sb[16];
  __shared__ float wgt[16];
  __shared__ __align__(16) unsigned short As[16][280];   // 16 x 256 k, stride 280 (bank-clean)
  __shared__ float f1s[16 * 132];
  if (t < 16) {
    const int idx = base + t;
    const int s = order[e * B_N + ((idx < n) ? idx : base)];
    sb[t] = s; wgt[t] = ew[s];
  }
  __syncthreads();
  const int lane = t & 63, wv = t >> 6;
  const int n16 = lane & 15, q = lane >> 4;
  const int oc0 = wv * 32 + n16;           // n-tile 2*wv
  const int oc1 = wv * 32 + 16 + n16;      // n-tile 2*wv+1
  const unsigned short* wb0 = w1r + ((size_t)(e * 128 + oc0)) * 4096 + q * 8;
  const unsigned short* wb1 = w1r + ((size_t)(e * 128 + oc1)) * 4096 + q * 8;
  f32x4 acc0 = {0.f, 0.f, 0.f, 0.f}, acc1 = {0.f, 0.f, 0.f, 0.f};
  const int ldrow = t >> 4, ldseg = t & 15;
  const unsigned short* asrc = h2b + (size_t)sb[ldrow] * 4096;
  uint4 r0 = *(const uint4*)(asrc + ldseg * 8);            // prefetch kc=0
  uint4 r1 = *(const uint4*)(asrc + (ldseg + 16) * 8);
  for (int kc = 0; kc < 4096; kc += 256) {
    *(uint4*)&As[ldrow][ldseg * 8] = r0;
    *(uint4*)&As[ldrow][(ldseg + 16) * 8] = r1;
    __syncthreads();
    if (kc + 256 < 4096) {                                 // prefetch next chunk (overlaps MFMA)
      r0 = *(const uint4*)(asrc + (kc + 256) + ldseg * 8);
      r1 = *(const uint4*)(asrc + (kc + 256) + (ldseg + 16) * 8);
    }
#pragma unroll
    for (int ks = 0; ks < 8; ++ks) {
      const short8 af = *(const short8*)&As[n16][ks * 32 + q * 8];   // A[m=n16][k]
      const short8 bf0 = *(const short8*)(wb0 + kc + ks * 32);       // B[k][n=oc0]
      const short8 bf1 = *(const short8*)(wb1 + kc + ks * 32);
      acc0 = __builtin_amdgcn_mfma_f32_16x16x32_bf16(af, bf0, acc0, 0, 0, 0);
      acc1 = __builtin_amdgcn_mfma_f32_16x16x32_bf16(af, bf1, acc1, 0, 0, 0);
    }
    __syncthreads();
  }
  // C layout: row m = q*4+r (sample), col = n16 (oc)
  const float* b1 = b1g + e * 128;
  const float bb0 = b1[oc0], bb1 = b1[oc1];
#pragma unroll
  for (int r = 0; r < 4; ++r) {
    const int m = q * 4 + r;
    f1s[m * 132 + oc0] = fmaxf(acc0[r] + bb0, 0.f);
    f1s[m * 132 + oc1] = fmaxf(acc1[r] + bb1, 0.f);
  }
  __syncthreads();
  int m = n - base; if (m > 16) m = 16;
  if (t < 160) {
    const int r = t / 10, o = t - r * 10;
    if (r < m) {
      const float* w2 = w2g + (e * 10 + o) * 128;
      float s = b2g[e * 10 + o];
#pragma unroll 8
      for (int c = 0; c < 128; ++c) s += f1s[r * 132 + c] * w2[c];
      outp[(size_t)sb[r] * 10 + o] = s * wgt[r];
    }
  }
}

extern "C" void kernel_launch(void* const* d_in, const int* in_sizes, int n_in,
                              void* d_out, int out_size, void* d_ws, size_t ws_size,
                              hipStream_t stream) {
  const float* x        = (const float*)d_in[0];
  const float* gw_conv  = (const float*)d_in[1];
  const float* gb_conv  = (const float*)d_in[2];
  const float* gw_fc    = (const float*)d_in[3];
  const float* gb_fc    = (const float*)d_in[4];
  const float* ew_conv1 = (const float*)d_in[5];
  const float* eb_conv1 = (const float*)d_in[6];
  const float* ew_conv2 = (const float*)d_in[7];
  const float* eb_conv2 = (const float*)d_in[8];
  const float* ew_fc1   = (const float*)d_in[9];
  const float* eb_fc1   = (const float*)d_in[10];
  const float* ew_fc2   = (const float*)d_in[11];
  const float* eb_fc2   = (const float*)d_in[12];
  float* out = (float*)d_out;
  float* ws  = (float*)d_ws;

  unsigned short* h2b = (unsigned short*)(ws + H2B_OFF);
  float* ew     = ws + EW_OFF;
  int*   order  = (int*)(ws + ORDER_OFF);
  int*   counts = (int*)(ws + CNT_OFF);
  unsigned short* w2r = (unsigned short*)(ws + W2R_OFF);
  unsigned short* w1r = (unsigned short*)(ws + W1R_OFF);
  unsigned short* w1c = (unsigned short*)(ws + W1C_OFF);

  k_front<<<2352, 256, 0, stream>>>(ew_fc1, w1r, ew_conv2, w2r, ew_conv1, w1c, counts);
  k_experts_conv<<<4096, 256, 0, stream>>>(x, gw_conv, gb_conv, gw_fc, gb_fc,
                                           w1c, eb_conv1, w2r, eb_conv2, h2b,
                                           out + 40960, ew, counts, order);
  k_fc<<<1024, 256, 0, stream>>>(h2b, w1r, eb_fc1, ew_fc2, eb_fc2,
                                 counts, order, ew, out);
}